// Round 4
// baseline (311.252 us; speedup 1.0000x reference)
//
#include <hip/hip_runtime.h>
#include <hip/hip_bf16.h>
#include <math.h>

#define NH 8
#define HD 64
#define CH 512
#define NT 1024
#define NB 8

typedef __bf16 bf16_t;
typedef bf16_t bf16x8 __attribute__((ext_vector_type(8)));
typedef bf16_t bf16x4 __attribute__((ext_vector_type(4)));
typedef float  f32x4  __attribute__((ext_vector_type(4)));
typedef float  f32x16 __attribute__((ext_vector_type(16)));

#define MFMA16(a, b, c) __builtin_amdgcn_mfma_f32_16x16x32_bf16((a), (b), (c), 0, 0, 0)
#define MFMA32(a, b, c) __builtin_amdgcn_mfma_f32_32x32x16_bf16((a), (b), (c), 0, 0, 0)

// additive bank skew: banks = 4*(r&7) + ((r>>3)&3) + colword -> full 32-cover,
// every wave64 LDS access <=2-way (free, m136)
#define SKW(r) (((r) >> 2) & 6)

__device__ __forceinline__ void gload16(const void* g, void* l) {
    __builtin_amdgcn_global_load_lds(
        (const __attribute__((address_space(1))) void*)g,
        (__attribute__((address_space(3))) void*)l, 16, 0, 0);
}

__device__ __forceinline__ float fexp2(float x) {
    float r;
    asm("v_exp_f32 %0, %1" : "=v"(r) : "v"(x));
    return r;
}

// ---------------------------------------------------------------------------
// prep: fp32 [C][N] -> bf16 [N][C] transpose (per 64x64 tile).
// ---------------------------------------------------------------------------
__global__ __launch_bounds__(256) void prep_kernel(
    const float* __restrict__ fc, const float* __restrict__ fp,
    const float* __restrict__ fn, bf16_t* __restrict__ Xc,
    bf16_t* __restrict__ Xn)
{
    __shared__ __align__(16) bf16_t tile[64 * 64];
    const int t = threadIdx.x;
    const int y = blockIdx.y;
    const int b = y / 3, ft = y % 3;
    const int c0 = (blockIdx.x & 7) * 64;
    const int n0 = (blockIdx.x >> 3) * 64;

    const float* src; bf16_t* dst;
    if (ft == 0)      { src = fc + (size_t)b * CH * NT; dst = Xc + (size_t)b * NT * CH; }
    else if (ft == 1) { src = fp + (size_t)b * CH * NT; dst = Xn + (size_t)b * 2 * NT * CH; }
    else              { src = fn + (size_t)b * CH * NT; dst = Xn + (size_t)b * 2 * NT * CH + (size_t)NT * CH; }

    const int nb = t & 15, cb = t >> 4;   // 4-wide chunks
    float4 ld[4];
#pragma unroll
    for (int i = 0; i < 4; ++i)
        ld[i] = *(const float4*)(src + (size_t)(c0 + cb * 4 + i) * NT + n0 + nb * 4);
    const float* lf = (const float*)ld;
#pragma unroll
    for (int j = 0; j < 4; ++j) {
        int n = nb * 4 + j;
        int v = (n >> 2) & 14;
        bf16x4 wv = { (bf16_t)lf[0 * 4 + j], (bf16_t)lf[1 * 4 + j],
                      (bf16_t)lf[2 * 4 + j], (bf16_t)lf[3 * 4 + j] };
        *(bf16x4*)(tile + n * 64 + ((cb ^ v) * 4)) = wv;
    }
    __syncthreads();
#pragma unroll
    for (int i = 0; i < 2; ++i) {
        int gid = t + i * 256;
        int n = gid >> 3, c16 = gid & 7;
        int v = (n >> 2) & 14;
        bf16x8 val = *(const bf16x8*)(tile + n * 64 + (((2 * c16) ^ v) * 4));
        *(bf16x8*)(dst + (size_t)(n0 + n) * CH + c0 + c16 * 8) = val;
    }
}

// weights fp32 -> bf16, grid (256, 4)
__global__ __launch_bounds__(256) void wcvt_kernel(
    const float* __restrict__ Wq, const float* __restrict__ Wk,
    const float* __restrict__ Wv, const float* __restrict__ Wo,
    bf16_t* __restrict__ Wb)
{
    const int m = blockIdx.y;
    const float* src = (m == 0) ? Wq : (m == 1) ? Wk : (m == 2) ? Wv : Wo;
    bf16_t* dst = Wb + (size_t)m * CH * CH;
    int gid = blockIdx.x * 256 + threadIdx.x;
    float4 v = *(const float4*)(src + (size_t)gid * 4);
    bf16x4 o = { (bf16_t)v.x, (bf16_t)v.y, (bf16_t)v.z, (bf16_t)v.w };
    *(bf16x4*)(dst + (size_t)gid * 4) = o;
}

// ---------------------------------------------------------------------------
// gemm_core: 128x128 tile, K=512, BK=32, all-bf16, global_load_lds staging.
// ---------------------------------------------------------------------------
template <bool SWAP>
__device__ __forceinline__ void gemm_core(const bf16_t* __restrict__ A,
                                          const bf16_t* __restrict__ B,
                                          bf16_t* aT, bf16_t* bT,
                                          f32x4 acc[4][4])
{
    const int t = threadIdx.x, w = t >> 6, lane = t & 63;
    const int lid = lane & 15, quad = lane >> 4;
    const int wm = w >> 1, wn = w & 1;
    const int l4 = lane >> 2, k4 = lane & 3;

    for (int kt = 0; kt < 16; ++kt) {
        const int k0 = kt * 32;
        __syncthreads();
#pragma unroll
        for (int i = 0; i < 2; ++i) {
            int q = w * 2 + i;
            int row = q * 16 + l4;
            int kk = k4 ^ ((row >> 1) & 3);
            gload16(A + (size_t)row * CH + k0 + kk * 8, aT + q * 512);
            gload16(B + (size_t)row * CH + k0 + kk * 8, bT + q * 512);
        }
        __syncthreads();

        const bf16_t* mT = SWAP ? bT : aT;
        const bf16_t* nT = SWAP ? aT : bT;
        bf16x8 mf[4], nf[4];
#pragma unroll
        for (int i = 0; i < 4; ++i) {
            int row = wm * 64 + i * 16 + lid;
            int kw = quad ^ ((row >> 1) & 3);
            mf[i] = *(const bf16x8*)(mT + row * 32 + kw * 8);
        }
#pragma unroll
        for (int i = 0; i < 4; ++i) {
            int row = wn * 64 + i * 16 + lid;
            int kw = quad ^ ((row >> 1) & 3);
            nf[i] = *(const bf16x8*)(nT + row * 32 + kw * 8);
        }
#pragma unroll
        for (int mi = 0; mi < 4; ++mi)
#pragma unroll
            for (int ni = 0; ni < 4; ++ni)
                acc[mi][ni] = MFMA16(mf[mi], nf[ni], acc[mi][ni]);
    }
}

// ---------------------------------------------------------------------------
// qkv: grid (160, 8)
// ---------------------------------------------------------------------------
__global__ __launch_bounds__(256) void qkv_kernel(
    const bf16_t* __restrict__ Xc, const bf16_t* __restrict__ Xn,
    const bf16_t* __restrict__ Wb,
    bf16_t* __restrict__ Qn, bf16_t* __restrict__ Kn, bf16_t* __restrict__ Vt)
{
    __shared__ __align__(16) bf16_t aT[128 * 32];
    __shared__ __align__(16) bf16_t bT[128 * 32];
    const int bx = blockIdx.x, b = blockIdx.y;
    const int t = threadIdx.x, w = t >> 6, lane = t & 63;
    const int lid = lane & 15, quad = lane >> 4;
    const int wm = w >> 1, wn = w & 1;
    const float QSC = 0.125f * 1.44269504f;

    f32x4 acc[4][4] = {};

    if (bx < 96) {
        const bf16_t* A; const bf16_t* B; bf16_t* O; float scale;
        if (bx < 32) {
            int nt = bx >> 2, ct = bx & 3;
            A = Xc + (size_t)b * NT * CH + (size_t)nt * 128 * CH;
            B = Wb + (size_t)0 * CH * CH + (size_t)ct * 128 * CH;
            O = Qn + (size_t)b * NT * CH + (size_t)nt * 128 * CH + ct * 128;
            scale = QSC;
        } else {
            int j = bx - 32, nt = j >> 2, ct = j & 3;
            A = Xn + (size_t)b * 2 * NT * CH + (size_t)nt * 128 * CH;
            B = Wb + (size_t)1 * CH * CH + (size_t)ct * 128 * CH;
            O = Kn + (size_t)b * 2 * NT * CH + (size_t)nt * 128 * CH + ct * 128;
            scale = 1.0f;
        }
        gemm_core<false>(A, B, aT, bT, acc);
#pragma unroll
        for (int mi = 0; mi < 4; ++mi)
#pragma unroll
            for (int ni = 0; ni < 4; ++ni)
#pragma unroll
                for (int r = 0; r < 4; ++r) {
                    int n  = wm * 64 + mi * 16 + quad * 4 + r;
                    int co = wn * 64 + ni * 16 + lid;
                    O[(size_t)n * CH + co] = (bf16_t)(acc[mi][ni][r] * scale);
                }
    } else {
        int j = bx - 96, nt = j >> 2, ct = j & 3;
        const bf16_t* A = Xn + (size_t)b * 2 * NT * CH + (size_t)nt * 128 * CH;
        const bf16_t* B = Wb + (size_t)2 * CH * CH + (size_t)ct * 128 * CH;
        bf16_t* O = Vt + (size_t)b * CH * 2 * NT + (size_t)ct * 128 * 2 * NT + nt * 128;
        gemm_core<true>(A, B, aT, bT, acc);
#pragma unroll
        for (int mi = 0; mi < 4; ++mi)
#pragma unroll
            for (int ni = 0; ni < 4; ++ni)
#pragma unroll
                for (int r = 0; r < 4; ++r) {
                    int co_l  = wm * 64 + mi * 16 + quad * 4 + r;
                    int key_l = wn * 64 + ni * 16 + lid;
                    O[(size_t)co_l * (2 * NT) + key_l] = (bf16_t)acc[mi][ni][r];
                }
    }
}

// ---------------------------------------------------------------------------
// attn: S^T formulation, 32x32x16 MFMA, no-max softmax.
// NEW: separate K/V LDS buffers -> 2 barriers/kt; additive bank skew;
// v_exp_f32 inline; K+V register prefetch spans whole compute phase.
// ---------------------------------------------------------------------------
__global__ __launch_bounds__(256) void attn_kernel(
    const bf16_t* __restrict__ Qn, const bf16_t* __restrict__ Kn,
    const bf16_t* __restrict__ Vt, bf16_t* __restrict__ AOn)
{
    __shared__ __align__(16) bf16_t k_lds[128 * 72];   // K tile [key][d]
    __shared__ __align__(16) bf16_t v_lds[64 * 136];   // V tile [d][key]
    __shared__ __align__(16) float  pqf[9216];         // Q-stage / P strips / O scratch
    __shared__ float l_scr[128];
    bf16_t* pq = (bf16_t*)pqf;

    const int t = threadIdx.x;
    const int w = t >> 6, lane = t & 63;
    const int wq = w >> 1, wk = w & 1;
    const int l31 = lane & 31, h = lane >> 5;

    const int q0 = blockIdx.x * 128;
    const int hh = blockIdx.y, b = blockIdx.z;

    const bf16_t* Qb  = Qn + ((size_t)b * NT + q0) * CH + hh * HD;
    const bf16_t* Kb  = Kn + (size_t)b * 2 * NT * CH + hh * HD;
    const bf16_t* Vtb = Vt + ((size_t)b * CH + hh * HD) * (2 * NT);
    bf16_t* AOb = AOn + ((size_t)b * NT + q0) * CH + hh * HD;

    // ---- stage Q [128][64] ----
    {
        int qr = t >> 3, c8 = (t & 7) * 8;
#pragma unroll
        for (int i = 0; i < 4; ++i) {
            int row = qr + i * 32;
            *(bf16x8*)(pq + row * 72 + c8 + SKW(row)) =
                *(const bf16x8*)(Qb + (size_t)row * CH + c8);
        }
    }
    __syncthreads();

    // Q B-frags to registers
    bf16x8 qf[2][4];
#pragma unroll
    for (int nf = 0; nf < 2; ++nf)
#pragma unroll
        for (int ks = 0; ks < 4; ++ks) {
            int row = wq * 64 + nf * 32 + l31;
            qf[nf][ks] = *(const bf16x8*)(pq + row * 72 + ks * 16 + h * 8 + SKW(row));
        }
    __syncthreads();   // pq becomes P space

    bf16_t* pw = pq + w * 4608;   // per-wave P strip [64 q][72]

    // loop-invariant staging geometry
    const int kr0 = t >> 3, kc8 = (t & 7) * 8;
    const int dr0 = t >> 4, vc8 = (t & 15) * 8;
    const bf16_t* kg = Kb + (size_t)kr0 * CH + kc8;
    const bf16_t* vg = Vtb + (size_t)dr0 * (2 * NT) + vc8;

    bf16x8 kreg[4], vreg[4];
#pragma unroll
    for (int i = 0; i < 4; ++i) kreg[i] = *(const bf16x8*)(kg + (size_t)i * 32 * CH);
#pragma unroll
    for (int i = 0; i < 4; ++i) vreg[i] = *(const bf16x8*)(vg + (size_t)i * 16 * (2 * NT));
    kg += (size_t)128 * CH; vg += 128;

    f32x16 o[2][2] = {};
    float lpart[2] = {0.f, 0.f};

    for (int kt = 0; kt < 16; ++kt) {
        __syncthreads();            // prev tile fully consumed by all waves
#pragma unroll
        for (int i = 0; i < 4; ++i) {
            int row = kr0 + i * 32;
            *(bf16x8*)(k_lds + row * 72 + kc8 + SKW(row)) = kreg[i];
        }
#pragma unroll
        for (int i = 0; i < 4; ++i) {
            int row = dr0 + i * 16;
            *(bf16x8*)(v_lds + row * 136 + vc8 + SKW(row)) = vreg[i];
        }
        __syncthreads();            // staging visible

        if (kt != 15) {             // prefetch next tile (overlaps all compute)
#pragma unroll
            for (int i = 0; i < 4; ++i) kreg[i] = *(const bf16x8*)(kg + (size_t)i * 32 * CH);
#pragma unroll
            for (int i = 0; i < 4; ++i) vreg[i] = *(const bf16x8*)(vg + (size_t)i * 16 * (2 * NT));
            kg += (size_t)128 * CH; vg += 128;
        }

        // ---- S^T = K Q^T ----
        f32x16 s[2][2] = {};
#pragma unroll
        for (int ks = 0; ks < 4; ++ks) {
            bf16x8 af[2];
#pragma unroll
            for (int mf = 0; mf < 2; ++mf) {
                int arow = wk * 64 + mf * 32 + l31;
                af[mf] = *(const bf16x8*)(k_lds + arow * 72 + ks * 16 + h * 8 + SKW(arow));
            }
#pragma unroll
            for (int mf = 0; mf < 2; ++mf)
#pragma unroll
                for (int nf = 0; nf < 2; ++nf)
                    s[mf][nf] = MFMA32(af[mf], qf[nf][ks], s[mf][nf]);
        }

        // ---- exp2 (v_exp_f32), l accumulation, P^T -> own LDS strip ----
#pragma unroll
        for (int mf = 0; mf < 2; ++mf)
#pragma unroll
            for (int nf = 0; nf < 2; ++nf) {
                int qrow = nf * 32 + l31;
#pragma unroll
                for (int g = 0; g < 4; ++g) {
                    float p0 = fexp2(s[mf][nf][4 * g + 0]);
                    float p1 = fexp2(s[mf][nf][4 * g + 1]);
                    float p2 = fexp2(s[mf][nf][4 * g + 2]);
                    float p3 = fexp2(s[mf][nf][4 * g + 3]);
                    lpart[nf] += (p0 + p1) + (p2 + p3);
                    bf16x4 pk = { (bf16_t)p0, (bf16_t)p1, (bf16_t)p2, (bf16_t)p3 };
                    int kb = mf * 32 + 8 * g + 4 * h;
                    *(bf16x4*)(pw + qrow * 72 + kb + SKW(qrow)) = pk;
                }
            }

        // ---- O^T += V^T P^T (own strip: wave-local, no barrier) ----
#pragma unroll
        for (int ks = 0; ks < 4; ++ks) {
            bf16x8 av[2], bp[2];
#pragma unroll
            for (int df = 0; df < 2; ++df) {
                int vrow = df * 32 + l31;
                av[df] = *(const bf16x8*)(v_lds + vrow * 136 + wk * 64 + ks * 16 + h * 8 + SKW(vrow));
            }
#pragma unroll
            for (int nf = 0; nf < 2; ++nf) {
                int bq = nf * 32 + l31;
                bp[nf] = *(const bf16x8*)(pw + bq * 72 + ks * 16 + h * 8 + SKW(bq));
            }
#pragma unroll
            for (int df = 0; df < 2; ++df)
#pragma unroll
                for (int nf = 0; nf < 2; ++nf)
                    o[df][nf] = MFMA32(av[df], bp[nf], o[df][nf]);
        }
    }
    __syncthreads();   // all PV reads done before epilogue reuses pqf

    // ---- combine across wk, divide by l, write out ----
    float l2[2];
#pragma unroll
    for (int nf = 0; nf < 2; ++nf)
        l2[nf] = lpart[nf] + __shfl_xor(lpart[nf], 32);

    if (wk == 1) {
        float* scr = pqf + wq * 4352;   // [64 q][68 d] f32
#pragma unroll
        for (int df = 0; df < 2; ++df)
#pragma unroll
            for (int nf = 0; nf < 2; ++nf) {
                int qrow = nf * 32 + l31;
#pragma unroll
                for (int g = 0; g < 4; ++g) {
                    int d = df * 32 + 8 * g + 4 * h;
                    f32x4 v = { o[df][nf][4 * g + 0], o[df][nf][4 * g + 1],
                                o[df][nf][4 * g + 2], o[df][nf][4 * g + 3] };
                    *(f32x4*)(scr + qrow * 68 + d) = v;
                }
            }
        if (h == 0) {
            l_scr[wq * 64 + 0 * 32 + l31] = l2[0];
            l_scr[wq * 64 + 1 * 32 + l31] = l2[1];
        }
    }
    __syncthreads();

    if (wk == 0) {
        const float* scr = pqf + wq * 4352;
        float inv[2];
#pragma unroll
        for (int nf = 0; nf < 2; ++nf)
            inv[nf] = 1.0f / (l2[nf] + l_scr[wq * 64 + nf * 32 + l31]);
#pragma unroll
        for (int df = 0; df < 2; ++df)
#pragma unroll
            for (int nf = 0; nf < 2; ++nf) {
                int qrow = nf * 32 + l31;
#pragma unroll
                for (int g = 0; g < 4; ++g) {
                    int d = df * 32 + 8 * g + 4 * h;
                    f32x4 part = *(const f32x4*)(scr + qrow * 68 + d);
                    bf16x4 ov = {
                        (bf16_t)((o[df][nf][4 * g + 0] + part.x) * inv[nf]),
                        (bf16_t)((o[df][nf][4 * g + 1] + part.y) * inv[nf]),
                        (bf16_t)((o[df][nf][4 * g + 2] + part.z) * inv[nf]),
                        (bf16_t)((o[df][nf][4 * g + 3] + part.w) * inv[nf]) };
                    int qg = wq * 64 + qrow;
                    *(bf16x4*)(k_lds + qg * 72 + d + SKW(qg)) = ov;
                }
            }
    }
    __syncthreads();

    // coalesced readback [128 q][64 d] -> AO
    {
        int qr = t >> 3, c8 = (t & 7) * 8;
#pragma unroll
        for (int i = 0; i < 4; ++i) {
            int row = qr + i * 32;
            *(bf16x8*)(AOb + (size_t)row * CH + c8) =
                *(const bf16x8*)(k_lds + row * 72 + c8 + SKW(row));
        }
    }
}

// ---------------------------------------------------------------------------
// proj: Z^T[b][co][n] = (AO @ Wo^T)^T + f_curr[b][co][n]  (fp32). grid (32, 8)
// ---------------------------------------------------------------------------
__global__ __launch_bounds__(256) void proj_kernel(
    const bf16_t* __restrict__ AOn, const bf16_t* __restrict__ Wb,
    const float* __restrict__ fc, float* __restrict__ Zt)
{
    __shared__ __align__(16) bf16_t aT[128 * 32];
    __shared__ __align__(16) bf16_t bT[128 * 32];
    const int bx = blockIdx.x, b = blockIdx.y;
    const int nt = bx >> 2, ct = bx & 3;
    const int t = threadIdx.x, w = t >> 6, lane = t & 63;
    const int lid = lane & 15, quad = lane >> 4;
    const int wm = w >> 1, wn = w & 1;

    const bf16_t* A = AOn + (size_t)b * NT * CH + (size_t)nt * 128 * CH;
    const bf16_t* B = Wb + (size_t)3 * CH * CH + (size_t)ct * 128 * CH;

    f32x4 acc[4][4] = {};
    gemm_core<true>(A, B, aT, bT, acc);

    const size_t bofs = (size_t)b * CH * NT;
#pragma unroll
    for (int mi = 0; mi < 4; ++mi)
#pragma unroll
        for (int ni = 0; ni < 4; ++ni)
#pragma unroll
            for (int r = 0; r < 4; ++r) {
                int co_l = wm * 64 + mi * 16 + quad * 4 + r;
                int n_l  = wn * 64 + ni * 16 + lid;
                size_t idx = bofs + (size_t)(ct * 128 + co_l) * NT + nt * 128 + n_l;
                Zt[idx] = acc[mi][ni][r] + fc[idx];
            }
}

// ---------------------------------------------------------------------------
// ln2: fused stats + apply over Z^T.  grid (16, 8), block 256.
// thread (n = t&63, cg = t>>6); both passes n-coalesced; Zt re-read hits L2.
// ---------------------------------------------------------------------------
__global__ __launch_bounds__(256) void ln2_kernel(
    const float* __restrict__ Zt, const float* __restrict__ gamma,
    const float* __restrict__ beta, float* __restrict__ out)
{
    __shared__ float pS[256], pQ[256];
    __shared__ float mu_s[64], rs_s[64];
    const int b = blockIdx.y, n0 = blockIdx.x * 64;
    const int t = threadIdx.x;
    const int n = t & 63, cg = t >> 6;
    const float* Zb = Zt + (size_t)b * CH * NT + n0 + n;

    float s = 0.f, q = 0.f;
#pragma unroll 8
    for (int k = 0; k < 128; ++k) {
        int co = cg * 128 + k;
        float z = Zb[(size_t)co * NT];
        s += z; q += z * z;
    }
    pS[cg * 64 + n] = s; pQ[cg * 64 + n] = q;
    __syncthreads();
    if (t < 64) {
        float ss = 0.f, qq = 0.f;
#pragma unroll
        for (int i = 0; i < 4; ++i) { ss += pS[i * 64 + t]; qq += pQ[i * 64 + t]; }
        float mu  = ss * (1.0f / 512.0f);
        float var = qq * (1.0f / 512.0f) - mu * mu;
        mu_s[t] = mu;
        rs_s[t] = rsqrtf(var + 1e-5f);
    }
    __syncthreads();

    const float mu = mu_s[n], rs = rs_s[n];
    float* ob = out + (size_t)b * CH * NT + n0 + n;
#pragma unroll 8
    for (int k = 0; k < 128; ++k) {
        int co = cg * 128 + k;
        float z = Zb[(size_t)co * NT];
        ob[(size_t)co * NT] = (z - mu) * rs * gamma[co] + beta[co];
    }
}

// ---------------------------------------------------------------------------
extern "C" void kernel_launch(void* const* d_in, const int* in_sizes, int n_in,
                              void* d_out, int out_size, void* d_ws, size_t ws_size,
                              hipStream_t stream)
{
    (void)in_sizes; (void)n_in; (void)out_size; (void)ws_size;
    const float* fc    = (const float*)d_in[0];
    const float* fp    = (const float*)d_in[1];
    const float* fn    = (const float*)d_in[2];
    const float* Wq    = (const float*)d_in[3];
    const float* Wk    = (const float*)d_in[4];
    const float* Wv    = (const float*)d_in[5];
    const float* Wo    = (const float*)d_in[6];
    const float* gamma = (const float*)d_in[7];
    const float* beta  = (const float*)d_in[8];
    float* out = (float*)d_out;

    char* ws = (char*)d_ws;
    // Layout:
    //   Xn  [0,   16M)  bf16 ; Zt fp32 overlays after qkv
    //   Qn  [16M, 24M)
    //   Kn  [24M, 40M)
    //   Xc  [40M, 48M)  (AOn overlays: Xc dead after qkv)
    //   Vt  [48M, 64M)
    //   Wb  [64M, 66M)
    bf16_t* Xn  = (bf16_t*)(ws);
    bf16_t* Qn  = (bf16_t*)(ws + 16777216);
    bf16_t* Kn  = (bf16_t*)(ws + 25165824);
    bf16_t* Xc  = (bf16_t*)(ws + 41943040);
    bf16_t* AOn = Xc;
    bf16_t* Vt  = (bf16_t*)(ws + 50331648);
    bf16_t* Wb  = (bf16_t*)(ws + 67108864);
    float*  Zt  = (float*)(ws);

    prep_kernel<<<dim3(128, 24), 256, 0, stream>>>(fc, fp, fn, Xc, Xn);
    wcvt_kernel<<<dim3(256, 4), 256, 0, stream>>>(Wq, Wk, Wv, Wo, Wb);
    qkv_kernel<<<dim3(160, 8), 256, 0, stream>>>(Xc, Xn, Wb, Qn, Kn, Vt);
    attn_kernel<<<dim3(8, 8, 8), 256, 0, stream>>>(Qn, Kn, Vt, AOn);
    proj_kernel<<<dim3(32, 8), 256, 0, stream>>>(AOn, Wb, fc, Zt);
    ln2_kernel<<<dim3(16, 8), 256, 0, stream>>>(Zt, gamma, beta, out);
}

// Round 5
// 285.334 us; speedup vs baseline: 1.0908x; 1.0908x over previous
//
#include <hip/hip_runtime.h>
#include <hip/hip_bf16.h>
#include <math.h>

#define NH 8
#define HD 64
#define CH 512
#define NT 1024
#define NB 8

typedef __bf16 bf16_t;
typedef bf16_t bf16x8 __attribute__((ext_vector_type(8)));
typedef bf16_t bf16x4 __attribute__((ext_vector_type(4)));
typedef float  f32x4  __attribute__((ext_vector_type(4)));
typedef float  f32x16 __attribute__((ext_vector_type(16)));

#define MFMA16(a, b, c) __builtin_amdgcn_mfma_f32_16x16x32_bf16((a), (b), (c), 0, 0, 0)
#define MFMA32(a, b, c) __builtin_amdgcn_mfma_f32_32x32x16_bf16((a), (b), (c), 0, 0, 0)

__device__ __forceinline__ void gload16(const void* g, void* l) {
    __builtin_amdgcn_global_load_lds(
        (const __attribute__((address_space(1))) void*)g,
        (__attribute__((address_space(3))) void*)l, 16, 0, 0);
}

// ---------------------------------------------------------------------------
// prep: fp32 [C][N] -> bf16 [N][C] transpose (per 64x64 tile).
// ---------------------------------------------------------------------------
__global__ __launch_bounds__(256) void prep_kernel(
    const float* __restrict__ fc, const float* __restrict__ fp,
    const float* __restrict__ fn, bf16_t* __restrict__ Xc,
    bf16_t* __restrict__ Xn)
{
    __shared__ __align__(16) bf16_t tile[64 * 64];
    const int t = threadIdx.x;
    const int y = blockIdx.y;
    const int b = y / 3, ft = y % 3;
    const int c0 = (blockIdx.x & 7) * 64;
    const int n0 = (blockIdx.x >> 3) * 64;

    const float* src; bf16_t* dst;
    if (ft == 0)      { src = fc + (size_t)b * CH * NT; dst = Xc + (size_t)b * NT * CH; }
    else if (ft == 1) { src = fp + (size_t)b * CH * NT; dst = Xn + (size_t)b * 2 * NT * CH; }
    else              { src = fn + (size_t)b * CH * NT; dst = Xn + (size_t)b * 2 * NT * CH + (size_t)NT * CH; }

    const int nb = t & 15, cb = t >> 4;   // 4-wide chunks
    float4 ld[4];
#pragma unroll
    for (int i = 0; i < 4; ++i)
        ld[i] = *(const float4*)(src + (size_t)(c0 + cb * 4 + i) * NT + n0 + nb * 4);
    const float* lf = (const float*)ld;
#pragma unroll
    for (int j = 0; j < 4; ++j) {
        int n = nb * 4 + j;
        int v = (n >> 2) & 14;
        bf16x4 wv = { (bf16_t)lf[0 * 4 + j], (bf16_t)lf[1 * 4 + j],
                      (bf16_t)lf[2 * 4 + j], (bf16_t)lf[3 * 4 + j] };
        *(bf16x4*)(tile + n * 64 + ((cb ^ v) * 4)) = wv;
    }
    __syncthreads();
#pragma unroll
    for (int i = 0; i < 2; ++i) {
        int gid = t + i * 256;
        int n = gid >> 3, c16 = gid & 7;
        int v = (n >> 2) & 14;
        bf16x8 val = *(const bf16x8*)(tile + n * 64 + (((2 * c16) ^ v) * 4));
        *(bf16x8*)(dst + (size_t)(n0 + n) * CH + c0 + c16 * 8) = val;
    }
}

// weights fp32 -> bf16, grid (256, 4)
__global__ __launch_bounds__(256) void wcvt_kernel(
    const float* __restrict__ Wq, const float* __restrict__ Wk,
    const float* __restrict__ Wv, const float* __restrict__ Wo,
    bf16_t* __restrict__ Wb)
{
    const int m = blockIdx.y;
    const float* src = (m == 0) ? Wq : (m == 1) ? Wk : (m == 2) ? Wv : Wo;
    bf16_t* dst = Wb + (size_t)m * CH * CH;
    int gid = blockIdx.x * 256 + threadIdx.x;
    float4 v = *(const float4*)(src + (size_t)gid * 4);
    bf16x4 o = { (bf16_t)v.x, (bf16_t)v.y, (bf16_t)v.z, (bf16_t)v.w };
    *(bf16x4*)(dst + (size_t)gid * 4) = o;
}

// ---------------------------------------------------------------------------
// gemm_core2: 128(A-rows) x 256(B-rows) tile, K=512, BK=32, bf16,
// global_load_lds staging.  SWAP=false: m=A(128),n=B(256) -> acc[4][8].
// SWAP=true: m=B(256),n=A(128) -> acc[8][4].  acc flat [32] f32x4.
// ---------------------------------------------------------------------------
template <bool SWAP>
__device__ __forceinline__ void gemm_core2(const bf16_t* __restrict__ A,
                                           const bf16_t* __restrict__ B,
                                           bf16_t* aT, bf16_t* bT,
                                           f32x4* acc)
{
    constexpr int MC = SWAP ? 8 : 4;
    constexpr int NC = SWAP ? 4 : 8;
    const int t = threadIdx.x, w = t >> 6, lane = t & 63;
    const int lid = lane & 15, quad = lane >> 4;
    const int wm = w >> 1, wn = w & 1;
    const int l4 = lane >> 2, k4 = lane & 3;

    for (int kt = 0; kt < 16; ++kt) {
        const int k0 = kt * 32;
        __syncthreads();
#pragma unroll
        for (int i = 0; i < 2; ++i) {          // A: 8 chunks of 16 rows
            int q = w * 2 + i;
            int row = q * 16 + l4;
            int kk = k4 ^ ((row >> 1) & 3);
            gload16(A + (size_t)row * CH + k0 + kk * 8, aT + q * 512);
        }
#pragma unroll
        for (int i = 0; i < 4; ++i) {          // B: 16 chunks of 16 rows
            int q = w * 4 + i;
            int row = q * 16 + l4;
            int kk = k4 ^ ((row >> 1) & 3);
            gload16(B + (size_t)row * CH + k0 + kk * 8, bT + q * 512);
        }
        __syncthreads();

        const bf16_t* mT = SWAP ? bT : aT;
        const bf16_t* nT = SWAP ? aT : bT;
        bf16x8 mf[MC], nf[NC];
#pragma unroll
        for (int i = 0; i < MC; ++i) {
            int row = wm * (MC * 16) + i * 16 + lid;
            int kw = quad ^ ((row >> 1) & 3);
            mf[i] = *(const bf16x8*)(mT + row * 32 + kw * 8);
        }
#pragma unroll
        for (int i = 0; i < NC; ++i) {
            int row = wn * (NC * 16) + i * 16 + lid;
            int kw = quad ^ ((row >> 1) & 3);
            nf[i] = *(const bf16x8*)(nT + row * 32 + kw * 8);
        }
#pragma unroll
        for (int mi = 0; mi < MC; ++mi)
#pragma unroll
            for (int ni = 0; ni < NC; ++ni)
                acc[mi * NC + ni] = MFMA16(mf[mi], nf[ni], acc[mi * NC + ni]);
    }
}

// ---------------------------------------------------------------------------
// qkv: grid (80, 8).  bx<16: Q; 16..47: K; 48..79: V.
// Each block: 128 rows x 256 co (2 co-tiles) -> X staged once per 256 co.
// ---------------------------------------------------------------------------
__global__ __launch_bounds__(256) void qkv_kernel(
    const bf16_t* __restrict__ Xc, const bf16_t* __restrict__ Xn,
    const bf16_t* __restrict__ Wb,
    bf16_t* __restrict__ Qn, bf16_t* __restrict__ Kn, bf16_t* __restrict__ Vt)
{
    __shared__ __align__(16) bf16_t aT[128 * 32];
    __shared__ __align__(16) bf16_t bT[256 * 32];
    const int bx = blockIdx.x, b = blockIdx.y;
    const int t = threadIdx.x, w = t >> 6, lane = t & 63;
    const int lid = lane & 15, quad = lane >> 4;
    const int wm = w >> 1, wn = w & 1;
    const float QSC = 0.125f * 1.44269504f;

    f32x4 acc[32];
#pragma unroll
    for (int i = 0; i < 32; ++i) acc[i] = f32x4{0.f, 0.f, 0.f, 0.f};

    if (bx < 48) {                         // Q or K job (direct layout)
        const bf16_t* A; const bf16_t* B; bf16_t* O; float scale;
        if (bx < 16) {
            int nt = bx >> 1, cp = bx & 1;
            A = Xc + (size_t)b * NT * CH + (size_t)nt * 128 * CH;
            B = Wb + (size_t)0 * CH * CH + (size_t)cp * 256 * CH;
            O = Qn + (size_t)b * NT * CH + (size_t)nt * 128 * CH + cp * 256;
            scale = QSC;
        } else {
            int j = bx - 16, nt = j >> 1, cp = j & 1;
            A = Xn + (size_t)b * 2 * NT * CH + (size_t)nt * 128 * CH;
            B = Wb + (size_t)1 * CH * CH + (size_t)cp * 256 * CH;
            O = Kn + (size_t)b * 2 * NT * CH + (size_t)nt * 128 * CH + cp * 256;
            scale = 1.0f;
        }
        gemm_core2<false>(A, B, aT, bT, acc);
#pragma unroll
        for (int mi = 0; mi < 4; ++mi)
#pragma unroll
            for (int ni = 0; ni < 8; ++ni)
#pragma unroll
                for (int r = 0; r < 4; ++r) {
                    int n  = wm * 64 + mi * 16 + quad * 4 + r;
                    int co = wn * 128 + ni * 16 + lid;
                    O[(size_t)n * CH + co] = (bf16_t)(acc[mi * 8 + ni][r] * scale);
                }
    } else {                               // V job -> Vt[co][key]
        int j = bx - 48, nt = j >> 1, cp = j & 1;
        const bf16_t* A = Xn + (size_t)b * 2 * NT * CH + (size_t)nt * 128 * CH;
        const bf16_t* B = Wb + (size_t)2 * CH * CH + (size_t)cp * 256 * CH;
        bf16_t* O = Vt + (size_t)b * CH * 2 * NT + (size_t)cp * 256 * 2 * NT + nt * 128;
        gemm_core2<true>(A, B, aT, bT, acc);
#pragma unroll
        for (int mi = 0; mi < 8; ++mi)
#pragma unroll
            for (int ni = 0; ni < 4; ++ni)
#pragma unroll
                for (int r = 0; r < 4; ++r) {
                    int co_l  = wm * 128 + mi * 16 + quad * 4 + r;
                    int key_l = wn * 64 + ni * 16 + lid;
                    O[(size_t)co_l * (2 * NT) + key_l] = (bf16_t)acc[mi * 4 + ni][r];
                }
    }
}

// ---------------------------------------------------------------------------
// attn: round-3 version verbatim (measured 91 us).  S^T formulation,
// 32x32x16 MFMA, no-max softmax, shared K/V buffer, 4 barriers/kt.
// ---------------------------------------------------------------------------
__global__ __launch_bounds__(256) void attn_kernel(
    const bf16_t* __restrict__ Qn, const bf16_t* __restrict__ Kn,
    const bf16_t* __restrict__ Vt, bf16_t* __restrict__ AOn)
{
    __shared__ __align__(16) bf16_t kv[128 * 72];
    __shared__ __align__(16) float  pqf[9216];
    __shared__ float l_scr[128];

    bf16_t* pq = (bf16_t*)pqf;

    const int t = threadIdx.x;
    const int w = t >> 6, lane = t & 63;
    const int wq = w >> 1, wk = w & 1;
    const int l31 = lane & 31, h = lane >> 5;

    const int q0 = blockIdx.x * 128;
    const int hh = blockIdx.y, b = blockIdx.z;

    const bf16_t* Qb  = Qn + ((size_t)b * NT + q0) * CH + hh * HD;
    const bf16_t* Kb  = Kn + (size_t)b * 2 * NT * CH + hh * HD;
    const bf16_t* Vtb = Vt + ((size_t)b * CH + hh * HD) * (2 * NT);
    bf16_t* AOb = AOn + ((size_t)b * NT + q0) * CH + hh * HD;

#pragma unroll
    for (int i = 0; i < 4; ++i) {
        int gid = t + i * 256;
        int qr = gid >> 3, c8 = (gid & 7) * 8;
        *(bf16x8*)(pq + qr * 72 + (c8 ^ (qr & 24))) =
            *(const bf16x8*)(Qb + (size_t)qr * CH + c8);
    }
    __syncthreads();

    bf16x8 kreg[4];
#pragma unroll
    for (int i = 0; i < 4; ++i) {
        int gid = t + i * 256;
        int kr = gid >> 3, c8 = (gid & 7) * 8;
        kreg[i] = *(const bf16x8*)(Kb + (size_t)kr * CH + c8);
    }

    bf16x8 qf[2][4];
#pragma unroll
    for (int nf = 0; nf < 2; ++nf)
#pragma unroll
        for (int ks = 0; ks < 4; ++ks) {
            int row = wq * 64 + nf * 32 + l31;
            int col = (ks * 16 + h * 8) ^ (row & 24);
            qf[nf][ks] = *(const bf16x8*)(pq + row * 72 + col);
        }
    __syncthreads();

    bf16_t* pw = pq + w * 4608;

    f32x16 o[2][2] = {};
    float lpart[2] = {0.f, 0.f};

    for (int kt = 0; kt < 16; ++kt) {
        const int kbase = kt * 128;

#pragma unroll
        for (int i = 0; i < 4; ++i) {
            int gid = t + i * 256;
            int kr = gid >> 3, c8 = (gid & 7) * 8;
            *(bf16x8*)(kv + kr * 72 + (c8 ^ (kr & 24))) = kreg[i];
        }
        __syncthreads();

        bf16x8 vreg[4];
#pragma unroll
        for (int i = 0; i < 4; ++i) {
            int gid = t + i * 256;
            int dr = gid >> 4, c8 = (gid & 15) * 8;
            vreg[i] = *(const bf16x8*)(Vtb + (size_t)dr * (2 * NT) + kbase + c8);
        }

        f32x16 s[2][2] = {};
#pragma unroll
        for (int ks = 0; ks < 4; ++ks) {
            bf16x8 af[2];
#pragma unroll
            for (int mf = 0; mf < 2; ++mf) {
                int arow = wk * 64 + mf * 32 + l31;
                int acol = (ks * 16 + h * 8) ^ (arow & 24);
                af[mf] = *(const bf16x8*)(kv + arow * 72 + acol);
            }
#pragma unroll
            for (int mf = 0; mf < 2; ++mf)
#pragma unroll
                for (int nf = 0; nf < 2; ++nf)
                    s[mf][nf] = MFMA32(af[mf], qf[nf][ks], s[mf][nf]);
        }

#pragma unroll
        for (int mf = 0; mf < 2; ++mf)
#pragma unroll
            for (int nf = 0; nf < 2; ++nf) {
                int qrow = nf * 32 + l31;
#pragma unroll
                for (int g = 0; g < 4; ++g) {
                    float p0 = exp2f(s[mf][nf][4 * g + 0]);
                    float p1 = exp2f(s[mf][nf][4 * g + 1]);
                    float p2 = exp2f(s[mf][nf][4 * g + 2]);
                    float p3 = exp2f(s[mf][nf][4 * g + 3]);
                    lpart[nf] += (p0 + p1) + (p2 + p3);
                    bf16x4 pk = { (bf16_t)p0, (bf16_t)p1, (bf16_t)p2, (bf16_t)p3 };
                    int kb = mf * 32 + 8 * g + 4 * h;
                    *(bf16x4*)(pw + qrow * 72 + (kb ^ (qrow & 24))) = pk;
                }
            }
        __syncthreads();

#pragma unroll
        for (int i = 0; i < 4; ++i) {
            int gid = t + i * 256;
            int dr = gid >> 4, c8 = (gid & 15) * 8;
            *(bf16x8*)(kv + dr * 136 + (c8 ^ (dr & 24))) = vreg[i];
        }
        __syncthreads();

        const int nb2 = (kt < 15) ? kbase + 128 : kbase;
#pragma unroll
        for (int i = 0; i < 4; ++i) {
            int gid = t + i * 256;
            int kr = gid >> 3, c8 = (gid & 7) * 8;
            kreg[i] = *(const bf16x8*)(Kb + (size_t)(nb2 + kr) * CH + c8);
        }

#pragma unroll
        for (int ks = 0; ks < 4; ++ks) {
            bf16x8 av[2], bp[2];
#pragma unroll
            for (int df = 0; df < 2; ++df) {
                int vrow = df * 32 + l31;
                int vcol = (wk * 64 + ks * 16 + h * 8) ^ (vrow & 24);
                av[df] = *(const bf16x8*)(kv + vrow * 136 + vcol);
            }
#pragma unroll
            for (int nf = 0; nf < 2; ++nf) {
                int bq = nf * 32 + l31;
                int bcol = (ks * 16 + h * 8) ^ (bq & 24);
                bp[nf] = *(const bf16x8*)(pw + bq * 72 + bcol);
            }
#pragma unroll
            for (int df = 0; df < 2; ++df)
#pragma unroll
                for (int nf = 0; nf < 2; ++nf)
                    o[df][nf] = MFMA32(av[df], bp[nf], o[df][nf]);
        }
        __syncthreads();
    }

    float l2[2];
#pragma unroll
    for (int nf = 0; nf < 2; ++nf)
        l2[nf] = lpart[nf] + __shfl_xor(lpart[nf], 32);

    if (wk == 1) {
        float* scr = pqf + wq * 4352;
#pragma unroll
        for (int df = 0; df < 2; ++df)
#pragma unroll
            for (int nf = 0; nf < 2; ++nf) {
                int qrow = nf * 32 + l31;
#pragma unroll
                for (int g = 0; g < 4; ++g) {
                    int d = df * 32 + 8 * g + 4 * h;
                    f32x4 v = { o[df][nf][4 * g + 0], o[df][nf][4 * g + 1],
                                o[df][nf][4 * g + 2], o[df][nf][4 * g + 3] };
                    *(f32x4*)(scr + qrow * 68 + d) = v;
                }
            }
        if (h == 0) {
            l_scr[wq * 64 + 0 * 32 + l31] = l2[0];
            l_scr[wq * 64 + 1 * 32 + l31] = l2[1];
        }
    }
    __syncthreads();

    if (wk == 0) {
        const float* scr = pqf + wq * 4352;
        float inv[2];
#pragma unroll
        for (int nf = 0; nf < 2; ++nf)
            inv[nf] = 1.0f / (l2[nf] + l_scr[wq * 64 + nf * 32 + l31]);
#pragma unroll
        for (int df = 0; df < 2; ++df)
#pragma unroll
            for (int nf = 0; nf < 2; ++nf) {
                int qrow = nf * 32 + l31;
#pragma unroll
                for (int g = 0; g < 4; ++g) {
                    int d = df * 32 + 8 * g + 4 * h;
                    f32x4 part = *(const f32x4*)(scr + qrow * 68 + d);
                    bf16x4 ov = {
                        (bf16_t)((o[df][nf][4 * g + 0] + part.x) * inv[nf]),
                        (bf16_t)((o[df][nf][4 * g + 1] + part.y) * inv[nf]),
                        (bf16_t)((o[df][nf][4 * g + 2] + part.z) * inv[nf]),
                        (bf16_t)((o[df][nf][4 * g + 3] + part.w) * inv[nf]) };
                    int qg = wq * 64 + qrow;
                    *(bf16x4*)(kv + qg * 72 + (d ^ (qg & 24))) = ov;
                }
            }
    }
    __syncthreads();

#pragma unroll
    for (int i = 0; i < 4; ++i) {
        int gid = t + i * 256;
        int qr = gid >> 3, c8 = (gid & 7) * 8;
        *(bf16x8*)(AOb + (size_t)qr * CH + c8) =
            *(const bf16x8*)(kv + qr * 72 + (c8 ^ (qr & 24)));
    }
}

// ---------------------------------------------------------------------------
// proj: Z^T[b][co][n] = (AO @ Wo^T)^T + f_curr[b][co][n]  (fp32).
// grid (16, 8): 128 n x 256 co per block (SWAP core).
// ---------------------------------------------------------------------------
__global__ __launch_bounds__(256) void proj_kernel(
    const bf16_t* __restrict__ AOn, const bf16_t* __restrict__ Wb,
    const float* __restrict__ fc, float* __restrict__ Zt)
{
    __shared__ __align__(16) bf16_t aT[128 * 32];
    __shared__ __align__(16) bf16_t bT[256 * 32];
    const int bx = blockIdx.x, b = blockIdx.y;
    const int nt = bx >> 1, cp = bx & 1;
    const int t = threadIdx.x, w = t >> 6, lane = t & 63;
    const int lid = lane & 15, quad = lane >> 4;
    const int wm = w >> 1, wn = w & 1;

    const bf16_t* A = AOn + (size_t)b * NT * CH + (size_t)nt * 128 * CH;
    const bf16_t* B = Wb + (size_t)3 * CH * CH + (size_t)cp * 256 * CH;

    f32x4 acc[32];
#pragma unroll
    for (int i = 0; i < 32; ++i) acc[i] = f32x4{0.f, 0.f, 0.f, 0.f};
    gemm_core2<true>(A, B, aT, bT, acc);

    const size_t bofs = (size_t)b * CH * NT;
#pragma unroll
    for (int mi = 0; mi < 8; ++mi)
#pragma unroll
        for (int ni = 0; ni < 4; ++ni)
#pragma unroll
            for (int r = 0; r < 4; ++r) {
                int co_l = wm * 128 + mi * 16 + quad * 4 + r;
                int n_l  = wn * 64 + ni * 16 + lid;
                size_t idx = bofs + (size_t)(cp * 256 + co_l) * NT + nt * 128 + n_l;
                Zt[idx] = acc[mi * 4 + ni][r] + fc[idx];
            }
}

// ---------------------------------------------------------------------------
// ln2: fused stats + apply over Z^T.  grid (16, 8), block 256.
// ---------------------------------------------------------------------------
__global__ __launch_bounds__(256) void ln2_kernel(
    const float* __restrict__ Zt, const float* __restrict__ gamma,
    const float* __restrict__ beta, float* __restrict__ out)
{
    __shared__ float pS[256], pQ[256];
    __shared__ float mu_s[64], rs_s[64];
    const int b = blockIdx.y, n0 = blockIdx.x * 64;
    const int t = threadIdx.x;
    const int n = t & 63, cg = t >> 6;
    const float* Zb = Zt + (size_t)b * CH * NT + n0 + n;

    float s = 0.f, q = 0.f;
#pragma unroll 8
    for (int k = 0; k < 128; ++k) {
        int co = cg * 128 + k;
        float z = Zb[(size_t)co * NT];
        s += z; q += z * z;
    }
    pS[cg * 64 + n] = s; pQ[cg * 64 + n] = q;
    __syncthreads();
    if (t < 64) {
        float ss = 0.f, qq = 0.f;
#pragma unroll
        for (int i = 0; i < 4; ++i) { ss += pS[i * 64 + t]; qq += pQ[i * 64 + t]; }
        float mu  = ss * (1.0f / 512.0f);
        float var = qq * (1.0f / 512.0f) - mu * mu;
        mu_s[t] = mu;
        rs_s[t] = rsqrtf(var + 1e-5f);
    }
    __syncthreads();

    const float mu = mu_s[n], rs = rs_s[n];
    float* ob = out + (size_t)b * CH * NT + n0 + n;
#pragma unroll 8
    for (int k = 0; k < 128; ++k) {
        int co = cg * 128 + k;
        float z = Zb[(size_t)co * NT];
        ob[(size_t)co * NT] = (z - mu) * rs * gamma[co] + beta[co];
    }
}

// ---------------------------------------------------------------------------
extern "C" void kernel_launch(void* const* d_in, const int* in_sizes, int n_in,
                              void* d_out, int out_size, void* d_ws, size_t ws_size,
                              hipStream_t stream)
{
    (void)in_sizes; (void)n_in; (void)out_size; (void)ws_size;
    const float* fc    = (const float*)d_in[0];
    const float* fp    = (const float*)d_in[1];
    const float* fn    = (const float*)d_in[2];
    const float* Wq    = (const float*)d_in[3];
    const float* Wk    = (const float*)d_in[4];
    const float* Wv    = (const float*)d_in[5];
    const float* Wo    = (const float*)d_in[6];
    const float* gamma = (const float*)d_in[7];
    const float* beta  = (const float*)d_in[8];
    float* out = (float*)d_out;

    char* ws = (char*)d_ws;
    // Layout:
    //   Xn  [0,   16M)  bf16 ; Zt fp32 overlays after qkv
    //   Qn  [16M, 24M)
    //   Kn  [24M, 40M)
    //   Xc  [40M, 48M)  (AOn overlays: Xc dead after qkv)
    //   Vt  [48M, 64M)
    //   Wb  [64M, 66M)
    bf16_t* Xn  = (bf16_t*)(ws);
    bf16_t* Qn  = (bf16_t*)(ws + 16777216);
    bf16_t* Kn  = (bf16_t*)(ws + 25165824);
    bf16_t* Xc  = (bf16_t*)(ws + 41943040);
    bf16_t* AOn = Xc;
    bf16_t* Vt  = (bf16_t*)(ws + 50331648);
    bf16_t* Wb  = (bf16_t*)(ws + 67108864);
    float*  Zt  = (float*)(ws);

    prep_kernel<<<dim3(128, 24), 256, 0, stream>>>(fc, fp, fn, Xc, Xn);
    wcvt_kernel<<<dim3(256, 4), 256, 0, stream>>>(Wq, Wk, Wv, Wo, Wb);
    qkv_kernel<<<dim3(80, 8), 256, 0, stream>>>(Xc, Xn, Wb, Qn, Kn, Vt);
    attn_kernel<<<dim3(8, 8, 8), 256, 0, stream>>>(Qn, Kn, Vt, AOn);
    proj_kernel<<<dim3(16, 8), 256, 0, stream>>>(AOn, Wb, fc, Zt);
    ln2_kernel<<<dim3(16, 8), 256, 0, stream>>>(Zt, gamma, beta, out);
}

// Round 6
// 267.468 us; speedup vs baseline: 1.1637x; 1.0668x over previous
//
#include <hip/hip_runtime.h>
#include <hip/hip_bf16.h>
#include <math.h>

#define NH 8
#define HD 64
#define CH 512
#define NT 1024
#define NB 8

typedef __bf16 bf16_t;
typedef bf16_t bf16x8 __attribute__((ext_vector_type(8)));
typedef bf16_t bf16x4 __attribute__((ext_vector_type(4)));
typedef float  f32x4  __attribute__((ext_vector_type(4)));
typedef float  f32x16 __attribute__((ext_vector_type(16)));

#define MFMA16(a, b, c) __builtin_amdgcn_mfma_f32_16x16x32_bf16((a), (b), (c), 0, 0, 0)
#define MFMA32(a, b, c) __builtin_amdgcn_mfma_f32_32x32x16_bf16((a), (b), (c), 0, 0, 0)

__device__ __forceinline__ void gload16(const void* g, void* l) {
    __builtin_amdgcn_global_load_lds(
        (const __attribute__((address_space(1))) void*)g,
        (__attribute__((address_space(3))) void*)l, 16, 0, 0);
}

__device__ __forceinline__ bf16x4 shfl32_b4(bf16x4 v) {
    union { bf16x4 v; int i[2]; } u;
    u.v = v;
    u.i[0] = __shfl_xor(u.i[0], 32, 64);
    u.i[1] = __shfl_xor(u.i[1], 32, 64);
    return u.v;
}

// ---------------------------------------------------------------------------
// prep: fp32 [C][N] -> bf16 [N][C] transpose (per 64x64 tile).
// ---------------------------------------------------------------------------
__global__ __launch_bounds__(256) void prep_kernel(
    const float* __restrict__ fc, const float* __restrict__ fp,
    const float* __restrict__ fn, bf16_t* __restrict__ Xc,
    bf16_t* __restrict__ Xn)
{
    __shared__ __align__(16) bf16_t tile[64 * 64];
    const int t = threadIdx.x;
    const int y = blockIdx.y;
    const int b = y / 3, ft = y % 3;
    const int c0 = (blockIdx.x & 7) * 64;
    const int n0 = (blockIdx.x >> 3) * 64;

    const float* src; bf16_t* dst;
    if (ft == 0)      { src = fc + (size_t)b * CH * NT; dst = Xc + (size_t)b * NT * CH; }
    else if (ft == 1) { src = fp + (size_t)b * CH * NT; dst = Xn + (size_t)b * 2 * NT * CH; }
    else              { src = fn + (size_t)b * CH * NT; dst = Xn + (size_t)b * 2 * NT * CH + (size_t)NT * CH; }

    const int nb = t & 15, cb = t >> 4;
    float4 ld[4];
#pragma unroll
    for (int i = 0; i < 4; ++i)
        ld[i] = *(const float4*)(src + (size_t)(c0 + cb * 4 + i) * NT + n0 + nb * 4);
    const float* lf = (const float*)ld;
#pragma unroll
    for (int j = 0; j < 4; ++j) {
        int n = nb * 4 + j;
        int v = (n >> 2) & 14;
        bf16x4 wv = { (bf16_t)lf[0 * 4 + j], (bf16_t)lf[1 * 4 + j],
                      (bf16_t)lf[2 * 4 + j], (bf16_t)lf[3 * 4 + j] };
        *(bf16x4*)(tile + n * 64 + ((cb ^ v) * 4)) = wv;
    }
    __syncthreads();
#pragma unroll
    for (int i = 0; i < 2; ++i) {
        int gid = t + i * 256;
        int n = gid >> 3, c16 = gid & 7;
        int v = (n >> 2) & 14;
        bf16x8 val = *(const bf16x8*)(tile + n * 64 + (((2 * c16) ^ v) * 4));
        *(bf16x8*)(dst + (size_t)(n0 + n) * CH + c0 + c16 * 8) = val;
    }
}

// weights fp32 -> bf16, grid (256, 4)
__global__ __launch_bounds__(256) void wcvt_kernel(
    const float* __restrict__ Wq, const float* __restrict__ Wk,
    const float* __restrict__ Wv, const float* __restrict__ Wo,
    bf16_t* __restrict__ Wb)
{
    const int m = blockIdx.y;
    const float* src = (m == 0) ? Wq : (m == 1) ? Wk : (m == 2) ? Wv : Wo;
    bf16_t* dst = Wb + (size_t)m * CH * CH;
    int gid = blockIdx.x * 256 + threadIdx.x;
    float4 v = *(const float4*)(src + (size_t)gid * 4);
    bf16x4 o = { (bf16_t)v.x, (bf16_t)v.y, (bf16_t)v.z, (bf16_t)v.w };
    *(bf16x4*)(dst + (size_t)gid * 4) = o;
}

// ---------------------------------------------------------------------------
// gemm_core: 128x128 tile, K=512, BK=32, all-bf16, global_load_lds staging.
// (round-3 version: measured best)
// ---------------------------------------------------------------------------
template <bool SWAP>
__device__ __forceinline__ void gemm_core(const bf16_t* __restrict__ A,
                                          const bf16_t* __restrict__ B,
                                          bf16_t* aT, bf16_t* bT,
                                          f32x4 acc[4][4])
{
    const int t = threadIdx.x, w = t >> 6, lane = t & 63;
    const int lid = lane & 15, quad = lane >> 4;
    const int wm = w >> 1, wn = w & 1;
    const int l4 = lane >> 2, k4 = lane & 3;

    for (int kt = 0; kt < 16; ++kt) {
        const int k0 = kt * 32;
        __syncthreads();
#pragma unroll
        for (int i = 0; i < 2; ++i) {
            int q = w * 2 + i;
            int row = q * 16 + l4;
            int kk = k4 ^ ((row >> 1) & 3);
            gload16(A + (size_t)row * CH + k0 + kk * 8, aT + q * 512);
            gload16(B + (size_t)row * CH + k0 + kk * 8, bT + q * 512);
        }
        __syncthreads();

        const bf16_t* mT = SWAP ? bT : aT;
        const bf16_t* nT = SWAP ? aT : bT;
        bf16x8 mf[4], nf[4];
#pragma unroll
        for (int i = 0; i < 4; ++i) {
            int row = wm * 64 + i * 16 + lid;
            int kw = quad ^ ((row >> 1) & 3);
            mf[i] = *(const bf16x8*)(mT + row * 32 + kw * 8);
        }
#pragma unroll
        for (int i = 0; i < 4; ++i) {
            int row = wn * 64 + i * 16 + lid;
            int kw = quad ^ ((row >> 1) & 3);
            nf[i] = *(const bf16x8*)(nT + row * 32 + kw * 8);
        }
#pragma unroll
        for (int mi = 0; mi < 4; ++mi)
#pragma unroll
            for (int ni = 0; ni < 4; ++ni)
                acc[mi][ni] = MFMA16(mf[mi], nf[ni], acc[mi][ni]);
    }
}

// ---------------------------------------------------------------------------
// qkv: grid (160, 8) — round-3 shape (reverted from 128x256)
// ---------------------------------------------------------------------------
__global__ __launch_bounds__(256) void qkv_kernel(
    const bf16_t* __restrict__ Xc, const bf16_t* __restrict__ Xn,
    const bf16_t* __restrict__ Wb,
    bf16_t* __restrict__ Qn, bf16_t* __restrict__ Kn, bf16_t* __restrict__ Vt)
{
    __shared__ __align__(16) bf16_t aT[128 * 32];
    __shared__ __align__(16) bf16_t bT[128 * 32];
    const int bx = blockIdx.x, b = blockIdx.y;
    const int t = threadIdx.x, w = t >> 6, lane = t & 63;
    const int lid = lane & 15, quad = lane >> 4;
    const int wm = w >> 1, wn = w & 1;
    const float QSC = 0.125f * 1.44269504f;

    f32x4 acc[4][4] = {};

    if (bx < 96) {
        const bf16_t* A; const bf16_t* B; bf16_t* O; float scale;
        if (bx < 32) {
            int nt = bx >> 2, ct = bx & 3;
            A = Xc + (size_t)b * NT * CH + (size_t)nt * 128 * CH;
            B = Wb + (size_t)0 * CH * CH + (size_t)ct * 128 * CH;
            O = Qn + (size_t)b * NT * CH + (size_t)nt * 128 * CH + ct * 128;
            scale = QSC;
        } else {
            int j = bx - 32, nt = j >> 2, ct = j & 3;
            A = Xn + (size_t)b * 2 * NT * CH + (size_t)nt * 128 * CH;
            B = Wb + (size_t)1 * CH * CH + (size_t)ct * 128 * CH;
            O = Kn + (size_t)b * 2 * NT * CH + (size_t)nt * 128 * CH + ct * 128;
            scale = 1.0f;
        }
        gemm_core<false>(A, B, aT, bT, acc);
#pragma unroll
        for (int mi = 0; mi < 4; ++mi)
#pragma unroll
            for (int ni = 0; ni < 4; ++ni)
#pragma unroll
                for (int r = 0; r < 4; ++r) {
                    int n  = wm * 64 + mi * 16 + quad * 4 + r;
                    int co = wn * 64 + ni * 16 + lid;
                    O[(size_t)n * CH + co] = (bf16_t)(acc[mi][ni][r] * scale);
                }
    } else {
        int j = bx - 96, nt = j >> 2, ct = j & 3;
        const bf16_t* A = Xn + (size_t)b * 2 * NT * CH + (size_t)nt * 128 * CH;
        const bf16_t* B = Wb + (size_t)2 * CH * CH + (size_t)ct * 128 * CH;
        bf16_t* O = Vt + (size_t)b * CH * 2 * NT + (size_t)ct * 128 * 2 * NT + nt * 128;
        gemm_core<true>(A, B, aT, bT, acc);
#pragma unroll
        for (int mi = 0; mi < 4; ++mi)
#pragma unroll
            for (int ni = 0; ni < 4; ++ni)
#pragma unroll
                for (int r = 0; r < 4; ++r) {
                    int co_l  = wm * 64 + mi * 16 + quad * 4 + r;
                    int key_l = wn * 64 + ni * 16 + lid;
                    O[(size_t)co_l * (2 * NT) + key_l] = (bf16_t)acc[mi][ni][r];
                }
    }
}

// ---------------------------------------------------------------------------
// attn: round-3 skeleton (4 barriers/kt, shared K/V buffer) with P kept in
// REGISTERS: S^T C/D -> PV B-frag via half-wave shfl_xor(32) + selects.
// Removes 16 b64 LDS writes + 8 b128 LDS reads per wave per kt.
// ---------------------------------------------------------------------------
__global__ __launch_bounds__(256) void attn_kernel(
    const bf16_t* __restrict__ Qn, const bf16_t* __restrict__ Kn,
    const bf16_t* __restrict__ Vt, bf16_t* __restrict__ AOn)
{
    __shared__ __align__(16) bf16_t kv[128 * 72];
    __shared__ __align__(16) float  pqf[9216];
    __shared__ float l_scr[128];

    bf16_t* pq = (bf16_t*)pqf;

    const int t = threadIdx.x;
    const int w = t >> 6, lane = t & 63;
    const int wq = w >> 1, wk = w & 1;
    const int l31 = lane & 31, h = lane >> 5;

    const int q0 = blockIdx.x * 128;
    const int hh = blockIdx.y, b = blockIdx.z;

    const bf16_t* Qb  = Qn + ((size_t)b * NT + q0) * CH + hh * HD;
    const bf16_t* Kb  = Kn + (size_t)b * 2 * NT * CH + hh * HD;
    const bf16_t* Vtb = Vt + ((size_t)b * CH + hh * HD) * (2 * NT);
    bf16_t* AOb = AOn + ((size_t)b * NT + q0) * CH + hh * HD;

#pragma unroll
    for (int i = 0; i < 4; ++i) {
        int gid = t + i * 256;
        int qr = gid >> 3, c8 = (gid & 7) * 8;
        *(bf16x8*)(pq + qr * 72 + (c8 ^ (qr & 24))) =
            *(const bf16x8*)(Qb + (size_t)qr * CH + c8);
    }
    __syncthreads();

    bf16x8 kreg[4];
#pragma unroll
    for (int i = 0; i < 4; ++i) {
        int gid = t + i * 256;
        int kr = gid >> 3, c8 = (gid & 7) * 8;
        kreg[i] = *(const bf16x8*)(Kb + (size_t)kr * CH + c8);
    }

    bf16x8 qf[2][4];
#pragma unroll
    for (int nf = 0; nf < 2; ++nf)
#pragma unroll
        for (int ks = 0; ks < 4; ++ks) {
            int row = wq * 64 + nf * 32 + l31;
            int col = (ks * 16 + h * 8) ^ (row & 24);
            qf[nf][ks] = *(const bf16x8*)(pq + row * 72 + col);
        }
    __syncthreads();

    f32x16 o[2][2] = {};
    float lpart[2] = {0.f, 0.f};

    for (int kt = 0; kt < 16; ++kt) {
        const int kbase = kt * 128;

#pragma unroll
        for (int i = 0; i < 4; ++i) {
            int gid = t + i * 256;
            int kr = gid >> 3, c8 = (gid & 7) * 8;
            *(bf16x8*)(kv + kr * 72 + (c8 ^ (kr & 24))) = kreg[i];
        }
        __syncthreads();

        bf16x8 vreg[4];
#pragma unroll
        for (int i = 0; i < 4; ++i) {
            int gid = t + i * 256;
            int dr = gid >> 4, c8 = (gid & 15) * 8;
            vreg[i] = *(const bf16x8*)(Vtb + (size_t)dr * (2 * NT) + kbase + c8);
        }

        // ---- S^T = K Q^T ----
        f32x16 s[2][2] = {};
#pragma unroll
        for (int ks = 0; ks < 4; ++ks) {
            bf16x8 af[2];
#pragma unroll
            for (int mf = 0; mf < 2; ++mf) {
                int arow = wk * 64 + mf * 32 + l31;
                int acol = (ks * 16 + h * 8) ^ (arow & 24);
                af[mf] = *(const bf16x8*)(kv + arow * 72 + acol);
            }
#pragma unroll
            for (int mf = 0; mf < 2; ++mf)
#pragma unroll
                for (int nf = 0; nf < 2; ++nf)
                    s[mf][nf] = MFMA32(af[mf], qf[nf][ks], s[mf][nf]);
        }

        // ---- exp2, l accumulation, pack P into registers ----
        bf16x4 P4[2][2][4];
#pragma unroll
        for (int mf = 0; mf < 2; ++mf)
#pragma unroll
            for (int nf = 0; nf < 2; ++nf) {
#pragma unroll
                for (int g = 0; g < 4; ++g) {
                    float p0 = exp2f(s[mf][nf][4 * g + 0]);
                    float p1 = exp2f(s[mf][nf][4 * g + 1]);
                    float p2 = exp2f(s[mf][nf][4 * g + 2]);
                    float p3 = exp2f(s[mf][nf][4 * g + 3]);
                    lpart[nf] += (p0 + p1) + (p2 + p3);
                    P4[mf][nf][g] = bf16x4{ (bf16_t)p0, (bf16_t)p1,
                                            (bf16_t)p2, (bf16_t)p3 };
                }
            }
        __syncthreads();   // all waves done reading K

        // stage V into kv as [64 d][136 keys]
#pragma unroll
        for (int i = 0; i < 4; ++i) {
            int gid = t + i * 256;
            int dr = gid >> 4, c8 = (gid & 15) * 8;
            *(bf16x8*)(kv + dr * 136 + (c8 ^ (dr & 24))) = vreg[i];
        }
        __syncthreads();

        // prefetch K(kt+1)
        const int nb2 = (kt < 15) ? kbase + 128 : kbase;
#pragma unroll
        for (int i = 0; i < 4; ++i) {
            int gid = t + i * 256;
            int kr = gid >> 3, c8 = (gid & 7) * 8;
            kreg[i] = *(const bf16x8*)(Kb + (size_t)(nb2 + kr) * CH + c8);
        }

        // ---- O^T += V^T P^T (P from registers via half-wave exchange) ----
        // B-frag (ks): k = ks*16 + h*8 + j; source reg group g=(ks&1)*2+h;
        // j0..3 from lane half 0, j4..7 from lane half 1.
#pragma unroll
        for (int ks = 0; ks < 4; ++ks) {
            const int mf = ks >> 1, gs = (ks & 1) * 2;
            bf16x8 av[2];
#pragma unroll
            for (int df = 0; df < 2; ++df) {
                int vrow = df * 32 + l31;
                int vcol = (wk * 64 + ks * 16 + h * 8) ^ (vrow & 24);
                av[df] = *(const bf16x8*)(kv + vrow * 136 + vcol);
            }
#pragma unroll
            for (int nf = 0; nf < 2; ++nf) {
                bf16x4 own = h ? P4[mf][nf][gs + 1] : P4[mf][nf][gs];
                bf16x4 snd = h ? P4[mf][nf][gs]     : P4[mf][nf][gs + 1];
                bf16x4 rcv = shfl32_b4(snd);
                bf16x4 lo = h ? rcv : own;   // j = 0..3  (from lane half 0)
                bf16x4 hi = h ? own : rcv;   // j = 4..7  (from lane half 1)
                bf16x8 bp = { lo[0], lo[1], lo[2], lo[3],
                              hi[0], hi[1], hi[2], hi[3] };
#pragma unroll
                for (int df = 0; df < 2; ++df)
                    o[df][nf] = MFMA32(av[df], bp, o[df][nf]);
            }
        }
        __syncthreads();
    }

    // ---- combine across wk, divide by l, write out ----
    float l2[2];
#pragma unroll
    for (int nf = 0; nf < 2; ++nf)
        l2[nf] = lpart[nf] + __shfl_xor(lpart[nf], 32);

    if (wk == 1) {
        float* scr = pqf + wq * 4352;
#pragma unroll
        for (int df = 0; df < 2; ++df)
#pragma unroll
            for (int nf = 0; nf < 2; ++nf) {
                int qrow = nf * 32 + l31;
#pragma unroll
                for (int g = 0; g < 4; ++g) {
                    int d = df * 32 + 8 * g + 4 * h;
                    f32x4 v = { o[df][nf][4 * g + 0], o[df][nf][4 * g + 1],
                                o[df][nf][4 * g + 2], o[df][nf][4 * g + 3] };
                    *(f32x4*)(scr + qrow * 68 + d) = v;
                }
            }
        if (h == 0) {
            l_scr[wq * 64 + 0 * 32 + l31] = l2[0];
            l_scr[wq * 64 + 1 * 32 + l31] = l2[1];
        }
    }
    __syncthreads();

    if (wk == 0) {
        const float* scr = pqf + wq * 4352;
        float inv[2];
#pragma unroll
        for (int nf = 0; nf < 2; ++nf)
            inv[nf] = 1.0f / (l2[nf] + l_scr[wq * 64 + nf * 32 + l31]);
#pragma unroll
        for (int df = 0; df < 2; ++df)
#pragma unroll
            for (int nf = 0; nf < 2; ++nf) {
                int qrow = nf * 32 + l31;
#pragma unroll
                for (int g = 0; g < 4; ++g) {
                    int d = df * 32 + 8 * g + 4 * h;
                    f32x4 part = *(const f32x4*)(scr + qrow * 68 + d);
                    bf16x4 ov = {
                        (bf16_t)((o[df][nf][4 * g + 0] + part.x) * inv[nf]),
                        (bf16_t)((o[df][nf][4 * g + 1] + part.y) * inv[nf]),
                        (bf16_t)((o[df][nf][4 * g + 2] + part.z) * inv[nf]),
                        (bf16_t)((o[df][nf][4 * g + 3] + part.w) * inv[nf]) };
                    int qg = wq * 64 + qrow;
                    *(bf16x4*)(kv + qg * 72 + (d ^ (qg & 24))) = ov;
                }
            }
    }
    __syncthreads();

#pragma unroll
    for (int i = 0; i < 4; ++i) {
        int gid = t + i * 256;
        int qr = gid >> 3, c8 = (gid & 7) * 8;
        *(bf16x8*)(AOb + (size_t)qr * CH + c8) =
            *(const bf16x8*)(kv + qr * 72 + (c8 ^ (qr & 24)));
    }
}

// ---------------------------------------------------------------------------
// proj: Z^T[b][co][n] = (AO @ Wo^T)^T + f_curr[b][co][n]  (fp32). grid (32, 8)
// ---------------------------------------------------------------------------
__global__ __launch_bounds__(256) void proj_kernel(
    const bf16_t* __restrict__ AOn, const bf16_t* __restrict__ Wb,
    const float* __restrict__ fc, float* __restrict__ Zt)
{
    __shared__ __align__(16) bf16_t aT[128 * 32];
    __shared__ __align__(16) bf16_t bT[128 * 32];
    const int bx = blockIdx.x, b = blockIdx.y;
    const int nt = bx >> 2, ct = bx & 3;
    const int t = threadIdx.x, w = t >> 6, lane = t & 63;
    const int lid = lane & 15, quad = lane >> 4;
    const int wm = w >> 1, wn = w & 1;

    const bf16_t* A = AOn + (size_t)b * NT * CH + (size_t)nt * 128 * CH;
    const bf16_t* B = Wb + (size_t)3 * CH * CH + (size_t)ct * 128 * CH;

    f32x4 acc[4][4] = {};
    gemm_core<true>(A, B, aT, bT, acc);

    const size_t bofs = (size_t)b * CH * NT;
#pragma unroll
    for (int mi = 0; mi < 4; ++mi)
#pragma unroll
        for (int ni = 0; ni < 4; ++ni)
#pragma unroll
            for (int r = 0; r < 4; ++r) {
                int co_l = wm * 64 + mi * 16 + quad * 4 + r;
                int n_l  = wn * 64 + ni * 16 + lid;
                size_t idx = bofs + (size_t)(ct * 128 + co_l) * NT + nt * 128 + n_l;
                Zt[idx] = acc[mi][ni][r] + fc[idx];
            }
}

// ---------------------------------------------------------------------------
// ln2: fused stats + apply over Z^T.  grid (16, 8), block 256.
// ---------------------------------------------------------------------------
__global__ __launch_bounds__(256) void ln2_kernel(
    const float* __restrict__ Zt, const float* __restrict__ gamma,
    const float* __restrict__ beta, float* __restrict__ out)
{
    __shared__ float pS[256], pQ[256];
    __shared__ float mu_s[64], rs_s[64];
    const int b = blockIdx.y, n0 = blockIdx.x * 64;
    const int t = threadIdx.x;
    const int n = t & 63, cg = t >> 6;
    const float* Zb = Zt + (size_t)b * CH * NT + n0 + n;

    float s = 0.f, q = 0.f;
#pragma unroll 8
    for (int k = 0; k < 128; ++k) {
        int co = cg * 128 + k;
        float z = Zb[(size_t)co * NT];
        s += z; q += z * z;
    }
    pS[cg * 64 + n] = s; pQ[cg * 64 + n] = q;
    __syncthreads();
    if (t < 64) {
        float ss = 0.f, qq = 0.f;
#pragma unroll
        for (int i = 0; i < 4; ++i) { ss += pS[i * 64 + t]; qq += pQ[i * 64 + t]; }
        float mu  = ss * (1.0f / 512.0f);
        float var = qq * (1.0f / 512.0f) - mu * mu;
        mu_s[t] = mu;
        rs_s[t] = rsqrtf(var + 1e-5f);
    }
    __syncthreads();

    const float mu = mu_s[n], rs = rs_s[n];
    float* ob = out + (size_t)b * CH * NT + n0 + n;
#pragma unroll 8
    for (int k = 0; k < 128; ++k) {
        int co = cg * 128 + k;
        float z = Zb[(size_t)co * NT];
        ob[(size_t)co * NT] = (z - mu) * rs * gamma[co] + beta[co];
    }
}

// ---------------------------------------------------------------------------
extern "C" void kernel_launch(void* const* d_in, const int* in_sizes, int n_in,
                              void* d_out, int out_size, void* d_ws, size_t ws_size,
                              hipStream_t stream)
{
    (void)in_sizes; (void)n_in; (void)out_size; (void)ws_size;
    const float* fc    = (const float*)d_in[0];
    const float* fp    = (const float*)d_in[1];
    const float* fn    = (const float*)d_in[2];
    const float* Wq    = (const float*)d_in[3];
    const float* Wk    = (const float*)d_in[4];
    const float* Wv    = (const float*)d_in[5];
    const float* Wo    = (const float*)d_in[6];
    const float* gamma = (const float*)d_in[7];
    const float* beta  = (const float*)d_in[8];
    float* out = (float*)d_out;

    char* ws = (char*)d_ws;
    // Layout:
    //   Xn  [0,   16M)  bf16 ; Zt fp32 overlays after qkv
    //   Qn  [16M, 24M)
    //   Kn  [24M, 40M)
    //   Xc  [40M, 48M)  (AOn overlays: Xc dead after qkv)
    //   Vt  [48M, 64M)
    //   Wb  [64M, 66M)
    bf16_t* Xn  = (bf16_t*)(ws);
    bf16_t* Qn  = (bf16_t*)(ws + 16777216);
    bf16_t* Kn  = (bf16_t*)(ws + 25165824);
    bf16_t* Xc  = (bf16_t*)(ws + 41943040);
    bf16_t* AOn = Xc;
    bf16_t* Vt  = (bf16_t*)(ws + 50331648);
    bf16_t* Wb  = (bf16_t*)(ws + 67108864);
    float*  Zt  = (float*)(ws);

    prep_kernel<<<dim3(128, 24), 256, 0, stream>>>(fc, fp, fn, Xc, Xn);
    wcvt_kernel<<<dim3(256, 4), 256, 0, stream>>>(Wq, Wk, Wv, Wo, Wb);
    qkv_kernel<<<dim3(160, 8), 256, 0, stream>>>(Xc, Xn, Wb, Qn, Kn, Vt);
    attn_kernel<<<dim3(8, 8, 8), 256, 0, stream>>>(Qn, Kn, Vt, AOn);
    proj_kernel<<<dim3(32, 8), 256, 0, stream>>>(AOn, Wb, fc, Zt);
    ln2_kernel<<<dim3(16, 8), 256, 0, stream>>>(Zt, gamma, beta, out);
}

// Round 7
// 256.655 us; speedup vs baseline: 1.2127x; 1.0421x over previous
//
#include <hip/hip_runtime.h>
#include <hip/hip_bf16.h>
#include <math.h>

#define NH 8
#define HD 64
#define CH 512
#define NT 1024
#define NB 8

typedef __bf16 bf16_t;
typedef bf16_t bf16x8 __attribute__((ext_vector_type(8)));
typedef bf16_t bf16x4 __attribute__((ext_vector_type(4)));
typedef float  f32x4  __attribute__((ext_vector_type(4)));
typedef float  f32x16 __attribute__((ext_vector_type(16)));

#define MFMA16(a, b, c) __builtin_amdgcn_mfma_f32_16x16x32_bf16((a), (b), (c), 0, 0, 0)
#define MFMA32(a, b, c) __builtin_amdgcn_mfma_f32_32x32x16_bf16((a), (b), (c), 0, 0, 0)

__device__ __forceinline__ void gload16(const void* g, void* l) {
    __builtin_amdgcn_global_load_lds(
        (const __attribute__((address_space(1))) void*)g,
        (__attribute__((address_space(3))) void*)l, 16, 0, 0);
}

// ---------------------------------------------------------------------------
// prep: fp32 [C][N] -> bf16 [N][C] transpose (per 64x64 tile), plus the
// weight fp32->bf16 conversion folded in as grid.y==24 (saves a launch).
// ---------------------------------------------------------------------------
__global__ __launch_bounds__(256) void prep_kernel(
    const float* __restrict__ fc, const float* __restrict__ fp,
    const float* __restrict__ fn, const float* __restrict__ Wq,
    const float* __restrict__ Wk, const float* __restrict__ Wv,
    const float* __restrict__ Wo, bf16_t* __restrict__ Xc,
    bf16_t* __restrict__ Xn, bf16_t* __restrict__ Wb)
{
    __shared__ __align__(16) bf16_t tile[64 * 64];
    const int t = threadIdx.x;
    const int y = blockIdx.y;

    if (y == 24) {                        // weight conversion job
        const int idx0 = blockIdx.x * 256 + t;       // float4 index
#pragma unroll
        for (int i = 0; i < 8; ++i) {
            int idx = idx0 + i * 32768;              // 0..262143
            int m = idx >> 16;                       // matrix (uniform per i)
            int off = idx & 65535;
            const float* src = (m == 0) ? Wq : (m == 1) ? Wk : (m == 2) ? Wv : Wo;
            float4 v = *(const float4*)(src + (size_t)off * 4);
            bf16x4 o = { (bf16_t)v.x, (bf16_t)v.y, (bf16_t)v.z, (bf16_t)v.w };
            *(bf16x4*)(Wb + (size_t)m * CH * CH + (size_t)off * 4) = o;
        }
        return;
    }

    const int b = y / 3, ft = y % 3;
    const int c0 = (blockIdx.x & 7) * 64;
    const int n0 = (blockIdx.x >> 3) * 64;

    const float* src; bf16_t* dst;
    if (ft == 0)      { src = fc + (size_t)b * CH * NT; dst = Xc + (size_t)b * NT * CH; }
    else if (ft == 1) { src = fp + (size_t)b * CH * NT; dst = Xn + (size_t)b * 2 * NT * CH; }
    else              { src = fn + (size_t)b * CH * NT; dst = Xn + (size_t)b * 2 * NT * CH + (size_t)NT * CH; }

    const int nb = t & 15, cb = t >> 4;
    float4 ld[4];
#pragma unroll
    for (int i = 0; i < 4; ++i)
        ld[i] = *(const float4*)(src + (size_t)(c0 + cb * 4 + i) * NT + n0 + nb * 4);
    const float* lf = (const float*)ld;
#pragma unroll
    for (int j = 0; j < 4; ++j) {
        int n = nb * 4 + j;
        int v = (n >> 2) & 14;
        bf16x4 wv = { (bf16_t)lf[0 * 4 + j], (bf16_t)lf[1 * 4 + j],
                      (bf16_t)lf[2 * 4 + j], (bf16_t)lf[3 * 4 + j] };
        *(bf16x4*)(tile + n * 64 + ((cb ^ v) * 4)) = wv;
    }
    __syncthreads();
#pragma unroll
    for (int i = 0; i < 2; ++i) {
        int gid = t + i * 256;
        int n = gid >> 3, c16 = gid & 7;
        int v = (n >> 2) & 14;
        bf16x8 val = *(const bf16x8*)(tile + n * 64 + (((2 * c16) ^ v) * 4));
        *(bf16x8*)(dst + (size_t)(n0 + n) * CH + c0 + c16 * 8) = val;
    }
}

// ---------------------------------------------------------------------------
// gemm_core: 128x128 tile, K=512, BK=32, all-bf16, global_load_lds staging.
// ---------------------------------------------------------------------------
template <bool SWAP>
__device__ __forceinline__ void gemm_core(const bf16_t* __restrict__ A,
                                          const bf16_t* __restrict__ B,
                                          bf16_t* aT, bf16_t* bT,
                                          f32x4 acc[4][4])
{
    const int t = threadIdx.x, w = t >> 6, lane = t & 63;
    const int lid = lane & 15, quad = lane >> 4;
    const int wm = w >> 1, wn = w & 1;
    const int l4 = lane >> 2, k4 = lane & 3;

    for (int kt = 0; kt < 16; ++kt) {
        const int k0 = kt * 32;
        __syncthreads();
#pragma unroll
        for (int i = 0; i < 2; ++i) {
            int q = w * 2 + i;
            int row = q * 16 + l4;
            int kk = k4 ^ ((row >> 1) & 3);
            gload16(A + (size_t)row * CH + k0 + kk * 8, aT + q * 512);
            gload16(B + (size_t)row * CH + k0 + kk * 8, bT + q * 512);
        }
        __syncthreads();

        const bf16_t* mT = SWAP ? bT : aT;
        const bf16_t* nT = SWAP ? aT : bT;
        bf16x8 mf[4], nf[4];
#pragma unroll
        for (int i = 0; i < 4; ++i) {
            int row = wm * 64 + i * 16 + lid;
            int kw = quad ^ ((row >> 1) & 3);
            mf[i] = *(const bf16x8*)(mT + row * 32 + kw * 8);
        }
#pragma unroll
        for (int i = 0; i < 4; ++i) {
            int row = wn * 64 + i * 16 + lid;
            int kw = quad ^ ((row >> 1) & 3);
            nf[i] = *(const bf16x8*)(nT + row * 32 + kw * 8);
        }
#pragma unroll
        for (int mi = 0; mi < 4; ++mi)
#pragma unroll
            for (int ni = 0; ni < 4; ++ni)
                acc[mi][ni] = MFMA16(mf[mi], nf[ni], acc[mi][ni]);
    }
}

// ---------------------------------------------------------------------------
// qkv: grid (160, 8).  XCD-aware remap: blocks sharing an X tile (same nt)
// have the same linear id mod 8 -> same XCD L2 (heuristic, perf-only).
// ---------------------------------------------------------------------------
__global__ __launch_bounds__(256) void qkv_kernel(
    const bf16_t* __restrict__ Xc, const bf16_t* __restrict__ Xn,
    const bf16_t* __restrict__ Wb,
    bf16_t* __restrict__ Qn, bf16_t* __restrict__ Kn, bf16_t* __restrict__ Vt)
{
    __shared__ __align__(16) bf16_t aT[128 * 32];
    __shared__ __align__(16) bf16_t bT[128 * 32];
    const int bx = blockIdx.x, b = blockIdx.y;
    const int t = threadIdx.x, w = t >> 6, lane = t & 63;
    const int lid = lane & 15, quad = lane >> 4;
    const int wm = w >> 1, wn = w & 1;
    const float QSC = 0.125f * 1.44269504f;

    f32x4 acc[4][4] = {};

    if (bx < 96) {
        const bf16_t* A; const bf16_t* B; bf16_t* O; float scale;
        if (bx < 32) {
            int nt = bx & 7, ct = bx >> 3;           // same nt -> same id%8
            A = Xc + (size_t)b * NT * CH + (size_t)nt * 128 * CH;
            B = Wb + (size_t)0 * CH * CH + (size_t)ct * 128 * CH;
            O = Qn + (size_t)b * NT * CH + (size_t)nt * 128 * CH + ct * 128;
            scale = QSC;
        } else {
            int j = bx - 32;
            int nt = (j & 7) + ((j >> 5) << 3);      // 0..15
            int ct = (j >> 3) & 3;
            A = Xn + (size_t)b * 2 * NT * CH + (size_t)nt * 128 * CH;
            B = Wb + (size_t)1 * CH * CH + (size_t)ct * 128 * CH;
            O = Kn + (size_t)b * 2 * NT * CH + (size_t)nt * 128 * CH + ct * 128;
            scale = 1.0f;
        }
        gemm_core<false>(A, B, aT, bT, acc);
#pragma unroll
        for (int mi = 0; mi < 4; ++mi)
#pragma unroll
            for (int ni = 0; ni < 4; ++ni)
#pragma unroll
                for (int r = 0; r < 4; ++r) {
                    int n  = wm * 64 + mi * 16 + quad * 4 + r;
                    int co = wn * 64 + ni * 16 + lid;
                    O[(size_t)n * CH + co] = (bf16_t)(acc[mi][ni][r] * scale);
                }
    } else {
        int j = bx - 96;
        int nt = (j & 7) + ((j >> 5) << 3);
        int ct = (j >> 3) & 3;
        const bf16_t* A = Xn + (size_t)b * 2 * NT * CH + (size_t)nt * 128 * CH;
        const bf16_t* B = Wb + (size_t)2 * CH * CH + (size_t)ct * 128 * CH;
        bf16_t* O = Vt + (size_t)b * CH * 2 * NT + (size_t)ct * 128 * 2 * NT + nt * 128;
        gemm_core<true>(A, B, aT, bT, acc);
#pragma unroll
        for (int mi = 0; mi < 4; ++mi)
#pragma unroll
            for (int ni = 0; ni < 4; ++ni)
#pragma unroll
                for (int r = 0; r < 4; ++r) {
                    int co_l  = wm * 64 + mi * 16 + quad * 4 + r;
                    int key_l = wn * 64 + ni * 16 + lid;
                    O[(size_t)co_l * (2 * NT) + key_l] = (bf16_t)acc[mi][ni][r];
                }
    }
}

// ---------------------------------------------------------------------------
// attn: r6 skeleton; the P C/D->B-frag exchange now uses
// v_permlane32_swap_b32 (gfx950): newA={A.lo,B.lo}, newB={A.hi,B.hi}
// gives bp = concat(X,Y) after 2 swaps - zero LDS-pipe ops, zero selects.
// ---------------------------------------------------------------------------
__global__ __launch_bounds__(256) void attn_kernel(
    const bf16_t* __restrict__ Qn, const bf16_t* __restrict__ Kn,
    const bf16_t* __restrict__ Vt, bf16_t* __restrict__ AOn)
{
    __shared__ __align__(16) bf16_t kv[128 * 72];
    __shared__ __align__(16) float  pqf[9216];
    __shared__ float l_scr[128];

    bf16_t* pq = (bf16_t*)pqf;

    const int t = threadIdx.x;
    const int w = t >> 6, lane = t & 63;
    const int wq = w >> 1, wk = w & 1;
    const int l31 = lane & 31, h = lane >> 5;

    const int q0 = blockIdx.x * 128;
    const int hh = blockIdx.y, b = blockIdx.z;

    const bf16_t* Qb  = Qn + ((size_t)b * NT + q0) * CH + hh * HD;
    const bf16_t* Kb  = Kn + (size_t)b * 2 * NT * CH + hh * HD;
    const bf16_t* Vtb = Vt + ((size_t)b * CH + hh * HD) * (2 * NT);
    bf16_t* AOb = AOn + ((size_t)b * NT + q0) * CH + hh * HD;

#pragma unroll
    for (int i = 0; i < 4; ++i) {
        int gid = t + i * 256;
        int qr = gid >> 3, c8 = (gid & 7) * 8;
        *(bf16x8*)(pq + qr * 72 + (c8 ^ (qr & 24))) =
            *(const bf16x8*)(Qb + (size_t)qr * CH + c8);
    }
    __syncthreads();

    bf16x8 kreg[4];
#pragma unroll
    for (int i = 0; i < 4; ++i) {
        int gid = t + i * 256;
        int kr = gid >> 3, c8 = (gid & 7) * 8;
        kreg[i] = *(const bf16x8*)(Kb + (size_t)kr * CH + c8);
    }

    bf16x8 qf[2][4];
#pragma unroll
    for (int nf = 0; nf < 2; ++nf)
#pragma unroll
        for (int ks = 0; ks < 4; ++ks) {
            int row = wq * 64 + nf * 32 + l31;
            int col = (ks * 16 + h * 8) ^ (row & 24);
            qf[nf][ks] = *(const bf16x8*)(pq + row * 72 + col);
        }
    __syncthreads();

    f32x16 o[2][2] = {};
    float lpart[2] = {0.f, 0.f};

    for (int kt = 0; kt < 16; ++kt) {
        const int kbase = kt * 128;

#pragma unroll
        for (int i = 0; i < 4; ++i) {
            int gid = t + i * 256;
            int kr = gid >> 3, c8 = (gid & 7) * 8;
            *(bf16x8*)(kv + kr * 72 + (c8 ^ (kr & 24))) = kreg[i];
        }
        __syncthreads();

        bf16x8 vreg[4];
#pragma unroll
        for (int i = 0; i < 4; ++i) {
            int gid = t + i * 256;
            int dr = gid >> 4, c8 = (gid & 15) * 8;
            vreg[i] = *(const bf16x8*)(Vtb + (size_t)dr * (2 * NT) + kbase + c8);
        }

        // ---- S^T = K Q^T ----
        f32x16 s[2][2] = {};
#pragma unroll
        for (int ks = 0; ks < 4; ++ks) {
            bf16x8 af[2];
#pragma unroll
            for (int mf = 0; mf < 2; ++mf) {
                int arow = wk * 64 + mf * 32 + l31;
                int acol = (ks * 16 + h * 8) ^ (arow & 24);
                af[mf] = *(const bf16x8*)(kv + arow * 72 + acol);
            }
#pragma unroll
            for (int mf = 0; mf < 2; ++mf)
#pragma unroll
                for (int nf = 0; nf < 2; ++nf)
                    s[mf][nf] = MFMA32(af[mf], qf[nf][ks], s[mf][nf]);
        }

        // ---- exp2, l accumulation, pack P into registers ----
        bf16x4 P4[2][2][4];
#pragma unroll
        for (int mf = 0; mf < 2; ++mf)
#pragma unroll
            for (int nf = 0; nf < 2; ++nf) {
#pragma unroll
                for (int g = 0; g < 4; ++g) {
                    float p0 = exp2f(s[mf][nf][4 * g + 0]);
                    float p1 = exp2f(s[mf][nf][4 * g + 1]);
                    float p2 = exp2f(s[mf][nf][4 * g + 2]);
                    float p3 = exp2f(s[mf][nf][4 * g + 3]);
                    lpart[nf] += (p0 + p1) + (p2 + p3);
                    P4[mf][nf][g] = bf16x4{ (bf16_t)p0, (bf16_t)p1,
                                            (bf16_t)p2, (bf16_t)p3 };
                }
            }
        __syncthreads();   // all waves done reading K

        // stage V into kv as [64 d][136 keys]
#pragma unroll
        for (int i = 0; i < 4; ++i) {
            int gid = t + i * 256;
            int dr = gid >> 4, c8 = (gid & 15) * 8;
            *(bf16x8*)(kv + dr * 136 + (c8 ^ (dr & 24))) = vreg[i];
        }
        __syncthreads();

        // prefetch K(kt+1)
        const int nb2 = (kt < 15) ? kbase + 128 : kbase;
#pragma unroll
        for (int i = 0; i < 4; ++i) {
            int gid = t + i * 256;
            int kr = gid >> 3, c8 = (gid & 7) * 8;
            kreg[i] = *(const bf16x8*)(Kb + (size_t)(nb2 + kr) * CH + c8);
        }

        // ---- O^T += V^T P^T; P exchange via v_permlane32_swap_b32 ----
#pragma unroll
        for (int ks = 0; ks < 4; ++ks) {
            const int mf = ks >> 1, gs = (ks & 1) * 2;
            bf16x8 av[2];
#pragma unroll
            for (int df = 0; df < 2; ++df) {
                int vrow = df * 32 + l31;
                int vcol = (wk * 64 + ks * 16 + h * 8) ^ (vrow & 24);
                av[df] = *(const bf16x8*)(kv + vrow * 136 + vcol);
            }
#pragma unroll
            for (int nf = 0; nf < 2; ++nf) {
                union { bf16x4 v; int d[2]; } X, Y;
                X.v = P4[mf][nf][gs];
                Y.v = P4[mf][nf][gs + 1];
                asm("v_permlane32_swap_b32 %0, %1"
                    : "+v"(X.d[0]), "+v"(Y.d[0]));
                asm("v_permlane32_swap_b32 %0, %1"
                    : "+v"(X.d[1]), "+v"(Y.d[1]));
                bf16x8 bp = { X.v[0], X.v[1], X.v[2], X.v[3],
                              Y.v[0], Y.v[1], Y.v[2], Y.v[3] };
#pragma unroll
                for (int df = 0; df < 2; ++df)
                    o[df][nf] = MFMA32(av[df], bp, o[df][nf]);
            }
        }
        __syncthreads();
    }

    // ---- combine across wk, divide by l, write out ----
    float l2[2];
#pragma unroll
    for (int nf = 0; nf < 2; ++nf)
        l2[nf] = lpart[nf] + __shfl_xor(lpart[nf], 32);

    if (wk == 1) {
        float* scr = pqf + wq * 4352;
#pragma unroll
        for (int df = 0; df < 2; ++df)
#pragma unroll
            for (int nf = 0; nf < 2; ++nf) {
                int qrow = nf * 32 + l31;
#pragma unroll
                for (int g = 0; g < 4; ++g) {
                    int d = df * 32 + 8 * g + 4 * h;
                    f32x4 v = { o[df][nf][4 * g + 0], o[df][nf][4 * g + 1],
                                o[df][nf][4 * g + 2], o[df][nf][4 * g + 3] };
                    *(f32x4*)(scr + qrow * 68 + d) = v;
                }
            }
        if (h == 0) {
            l_scr[wq * 64 + 0 * 32 + l31] = l2[0];
            l_scr[wq * 64 + 1 * 32 + l31] = l2[1];
        }
    }
    __syncthreads();

    if (wk == 0) {
        const float* scr = pqf + wq * 4352;
        float inv[2];
#pragma unroll
        for (int nf = 0; nf < 2; ++nf)
            inv[nf] = 1.0f / (l2[nf] + l_scr[wq * 64 + nf * 32 + l31]);
#pragma unroll
        for (int df = 0; df < 2; ++df)
#pragma unroll
            for (int nf = 0; nf < 2; ++nf) {
                int qrow = nf * 32 + l31;
#pragma unroll
                for (int g = 0; g < 4; ++g) {
                    int d = df * 32 + 8 * g + 4 * h;
                    f32x4 part = *(const f32x4*)(scr + qrow * 68 + d);
                    bf16x4 ov = {
                        (bf16_t)((o[df][nf][4 * g + 0] + part.x) * inv[nf]),
                        (bf16_t)((o[df][nf][4 * g + 1] + part.y) * inv[nf]),
                        (bf16_t)((o[df][nf][4 * g + 2] + part.z) * inv[nf]),
                        (bf16_t)((o[df][nf][4 * g + 3] + part.w) * inv[nf]) };
                    int qg = wq * 64 + qrow;
                    *(bf16x4*)(kv + qg * 72 + (d ^ (qg & 24))) = ov;
                }
            }
    }
    __syncthreads();

#pragma unroll
    for (int i = 0; i < 4; ++i) {
        int gid = t + i * 256;
        int qr = gid >> 3, c8 = (gid & 7) * 8;
        *(bf16x8*)(AOb + (size_t)qr * CH + c8) =
            *(const bf16x8*)(kv + qr * 72 + (c8 ^ (qr & 24)));
    }
}

// ---------------------------------------------------------------------------
// proj: Z^T[b][co][n] = (AO @ Wo^T)^T + f_curr[b][co][n]  (fp32). grid (32, 8)
// XCD remap: same nt (shared AO tile) -> same id%8.
// ---------------------------------------------------------------------------
__global__ __launch_bounds__(256) void proj_kernel(
    const bf16_t* __restrict__ AOn, const bf16_t* __restrict__ Wb,
    const float* __restrict__ fc, float* __restrict__ Zt)
{
    __shared__ __align__(16) bf16_t aT[128 * 32];
    __shared__ __align__(16) bf16_t bT[128 * 32];
    const int bx = blockIdx.x, b = blockIdx.y;
    const int nt = bx & 7, ct = bx >> 3;
    const int t = threadIdx.x, w = t >> 6, lane = t & 63;
    const int lid = lane & 15, quad = lane >> 4;
    const int wm = w >> 1, wn = w & 1;

    const bf16_t* A = AOn + (size_t)b * NT * CH + (size_t)nt * 128 * CH;
    const bf16_t* B = Wb + (size_t)3 * CH * CH + (size_t)ct * 128 * CH;

    f32x4 acc[4][4] = {};
    gemm_core<true>(A, B, aT, bT, acc);

    const size_t bofs = (size_t)b * CH * NT;
#pragma unroll
    for (int mi = 0; mi < 4; ++mi)
#pragma unroll
        for (int ni = 0; ni < 4; ++ni)
#pragma unroll
            for (int r = 0; r < 4; ++r) {
                int co_l = wm * 64 + mi * 16 + quad * 4 + r;
                int n_l  = wn * 64 + ni * 16 + lid;
                size_t idx = bofs + (size_t)(ct * 128 + co_l) * NT + nt * 128 + n_l;
                Zt[idx] = acc[mi][ni][r] + fc[idx];
            }
}

// ---------------------------------------------------------------------------
// ln2: fused stats + apply over Z^T.  grid (16, 8), block 256.
// ---------------------------------------------------------------------------
__global__ __launch_bounds__(256) void ln2_kernel(
    const float* __restrict__ Zt, const float* __restrict__ gamma,
    const float* __restrict__ beta, float* __restrict__ out)
{
    __shared__ float pS[256], pQ[256];
    __shared__ float mu_s[64], rs_s[64];
    const int b = blockIdx.y, n0 = blockIdx.x * 64;
    const int t = threadIdx.x;
    const int n = t & 63, cg = t >> 6;
    const float* Zb = Zt + (size_t)b * CH * NT + n0 + n;

    float s = 0.f, q = 0.f;
#pragma unroll 8
    for (int k = 0; k < 128; ++k) {
        int co = cg * 128 + k;
        float z = Zb[(size_t)co * NT];
        s += z; q += z * z;
    }
    pS[cg * 64 + n] = s; pQ[cg * 64 + n] = q;
    __syncthreads();
    if (t < 64) {
        float ss = 0.f, qq = 0.f;
#pragma unroll
        for (int i = 0; i < 4; ++i) { ss += pS[i * 64 + t]; qq += pQ[i * 64 + t]; }
        float mu  = ss * (1.0f / 512.0f);
        float var = qq * (1.0f / 512.0f) - mu * mu;
        mu_s[t] = mu;
        rs_s[t] = rsqrtf(var + 1e-5f);
    }
    __syncthreads();

    const float mu = mu_s[n], rs = rs_s[n];
    float* ob = out + (size_t)b * CH * NT + n0 + n;
#pragma unroll 8
    for (int k = 0; k < 128; ++k) {
        int co = cg * 128 + k;
        float z = Zb[(size_t)co * NT];
        ob[(size_t)co * NT] = (z - mu) * rs * gamma[co] + beta[co];
    }
}

// ---------------------------------------------------------------------------
extern "C" void kernel_launch(void* const* d_in, const int* in_sizes, int n_in,
                              void* d_out, int out_size, void* d_ws, size_t ws_size,
                              hipStream_t stream)
{
    (void)in_sizes; (void)n_in; (void)out_size; (void)ws_size;
    const float* fc    = (const float*)d_in[0];
    const float* fp    = (const float*)d_in[1];
    const float* fn    = (const float*)d_in[2];
    const float* Wq    = (const float*)d_in[3];
    const float* Wk    = (const float*)d_in[4];
    const float* Wv    = (const float*)d_in[5];
    const float* Wo    = (const float*)d_in[6];
    const float* gamma = (const float*)d_in[7];
    const float* beta  = (const float*)d_in[8];
    float* out = (float*)d_out;

    char* ws = (char*)d_ws;
    // Layout:
    //   Xn  [0,   16M)  bf16 ; Zt fp32 overlays after qkv
    //   Qn  [16M, 24M)
    //   Kn  [24M, 40M)
    //   Xc  [40M, 48M)  (AOn overlays: Xc dead after qkv)
    //   Vt  [48M, 64M)
    //   Wb  [64M, 66M)
    bf16_t* Xn  = (bf16_t*)(ws);
    bf16_t* Qn  = (bf16_t*)(ws + 16777216);
    bf16_t* Kn  = (bf16_t*)(ws + 25165824);
    bf16_t* Xc  = (bf16_t*)(ws + 41943040);
    bf16_t* AOn = Xc;
    bf16_t* Vt  = (bf16_t*)(ws + 50331648);
    bf16_t* Wb  = (bf16_t*)(ws + 67108864);
    float*  Zt  = (float*)(ws);

    prep_kernel<<<dim3(128, 25), 256, 0, stream>>>(fc, fp, fn, Wq, Wk, Wv, Wo, Xc, Xn, Wb);
    qkv_kernel<<<dim3(160, 8), 256, 0, stream>>>(Xc, Xn, Wb, Qn, Kn, Vt);
    attn_kernel<<<dim3(8, 8, 8), 256, 0, stream>>>(Qn, Kn, Vt, AOn);
    proj_kernel<<<dim3(32, 8), 256, 0, stream>>>(AOn, Wb, fc, Zt);
    ln2_kernel<<<dim3(16, 8), 256, 0, stream>>>(Zt, gamma, beta, out);
}